// Round 8
// baseline (1135.293 us; speedup 1.0000x reference)
//
#include <hip/hip_runtime.h>

#define NN 50000
#define EE 1600000

using u16 = unsigned short;
using u32 = unsigned int;
using u64 = unsigned long long;

typedef float f32x4 __attribute__((ext_vector_type(4)));
typedef float f32x2 __attribute__((ext_vector_type(2)));
typedef __bf16 bf16x8 __attribute__((ext_vector_type(8)));
typedef unsigned short u16x8 __attribute__((ext_vector_type(8)));

struct alignas(8) U16x4 { u16 a, b, c, d; };
struct PtrTab { const void* p[20]; };

// canonical fp32 weight-pad offsets
#define OW1 0
#define OB1 768
#define OG 896
#define OBB 1024
#define ORM 1152
#define ORV 1280
#define OW2 1408
#define OB2 17792
#define OCH0 17920
#define OCH1 42496
#define OCH2 54784
#define OCH3 67072
#define OCW1 79360
#define OCB1 144896
#define OCG 145152
#define OCBB 145408
#define OCRM 145664
#define OCRV 145920
#define OCW2 146176
#define OCB2 146688
#define OTOT 146690

// element offsets within d_out (dtype-independent in elements)
#define LG_OFF ((size_t)NN * 256)
#define EW_OFF ((size_t)NN * 256 + (size_t)NN * 2)

__device__ __forceinline__ float bf2f(u16 u) { return __builtin_bit_cast(float, (u32)u << 16); }
__device__ __forceinline__ float bfl(u32 u) { return __builtin_bit_cast(float, u << 16); }
__device__ __forceinline__ float bfh(u32 u) { return __builtin_bit_cast(float, u & 0xffff0000u); }
__device__ __forceinline__ u16 f2bf(float f) {
    u32 u = __builtin_bit_cast(u32, f);
    return (u16)((u + 0x7fffu + ((u >> 16) & 1u)) >> 16);
}

// Input dtype detector: flag=1 -> bf16 inputs, 0 -> fp32 inputs.
__global__ __launch_bounds__(256) void k_detect(const u16* __restrict__ f, int* __restrict__ flag) {
    __shared__ int bad;
    if (threadIdx.x == 0) bad = 0;
    __syncthreads();
    u16 u = f[threadIdx.x];
    int e = (u >> 7) & 0xFF;
    if (e >= 0x90) atomicAdd(&bad, 1);
    __syncthreads();
    if (threadIdx.x == 0) flag[0] = (bad < 16) ? 1 : 0;
}

// Convert all 20 weight arrays into canonical fp32 pad.
__global__ __launch_bounds__(256) void k_wconv(PtrTab tab, const int* __restrict__ flag,
                                               float* __restrict__ wpad) {
    const int SZ[20] = {768, 128, 128, 128, 128, 128, 16384, 128, 24576, 12288, 12288, 12288,
                        65536, 256, 256, 256, 256, 256, 512, 2};
    const int OF[20] = {OW1, OB1, OG, OBB, ORM, ORV, OW2, OB2, OCH0, OCH1, OCH2, OCH3,
                        OCW1, OCB1, OCG, OCBB, OCRM, OCRV, OCW2, OCB2};
    int a = blockIdx.x;
    int n = SZ[a];
    float* dst = wpad + OF[a];
    if (flag[0] != 0) {
        const u16* s = (const u16*)tab.p[a];
        for (int i = threadIdx.x; i < n; i += 256) dst[i] = bf2f(s[i]);
    } else {
        const float* s = (const float*)tab.p[a];
        for (int i = threadIdx.x; i < n; i += 256) dst[i] = s[i];
    }
}

// Fold PAE BN into W2 (MFMA B-frag swizzled bf16) + b2'. k-row permutation
// matches stage-1 MFMA output order in k_pae (kappa(kc,q,j), R6).
__global__ __launch_bounds__(128) void k_fold(const float* __restrict__ wpad,
                                              u16* __restrict__ W2s, float* __restrict__ b2p) {
    const float* g = wpad + OG;
    const float* b = wpad + OBB;
    const float* rm = wpad + ORM;
    const float* rv = wpad + ORV;
    const float* w2 = wpad + OW2;
    const float* b2 = wpad + OB2;
    int blk = blockIdx.x, tid = threadIdx.x;
    if (blk < 32) {
        int kc = blk >> 3, jt = blk & 7;
        int lane = tid & 63, jh = tid >> 6;
        int q = lane >> 4;
        for (int jj = 0; jj < 4; jj++) {
            int j = jh * 4 + jj;
            int k = kc * 32 + ((j < 4) ? (q * 4 + j) : (16 + q * 4 + (j - 4)));
            int jcol = jt * 16 + (lane & 15);
            float s = g[k] * rsqrtf(rv[k] + 1e-5f);
            W2s[((kc * 8 + jt) * 64 + lane) * 8 + j] = f2bf(s * w2[k * 128 + jcol]);
        }
    } else {
        if (tid < 128) {
            int j = tid;
            float acc = b2[j];
            for (int k = 0; k < 128; k++) {
                float s = g[k] * rsqrtf(rv[k] + 1e-5f);
                float t = b[k] - rm[k] * s;
                acc += t * w2[k * 128 + j];
            }
            b2p[j] = acc;
        }
    }
}

// Fold classifier weights: W1c = cls_w1 as MFMA B-fragments (bf16, phase-sliced),
// w2p[j][c] = s_j * cls_w2[j][c], b2p2[c] = cls_b2[c] + sum_j t_j * cls_w2[j][c].
__global__ __launch_bounds__(256) void k_foldc(const float* __restrict__ wpad,
                                               u16* __restrict__ W1c, float* __restrict__ w2p,
                                               float* __restrict__ b2p2) {
    int tid = threadIdx.x;
    if (blockIdx.x < 64) {
        const float* w1 = wpad + OCW1;
        int base = blockIdx.x * 1024 + tid * 4;
#pragma unroll
        for (int u = 0; u < 4; u++) {
            int gi = base + u;
            int j = gi & 7;
            int lane = (gi >> 3) & 63;
            int ct = (gi >> 9) & 15;
            int kc2 = (gi >> 13) & 1;
            int l = gi >> 14;
            int k = l * 64 + kc2 * 32 + ((lane >> 4) & 3) * 8 + j;
            int col = ct * 16 + (lane & 15);
            W1c[gi] = f2bf(w1[k * 256 + col]);
        }
    } else {
        __shared__ float red[8];
        int j = tid;
        float s = wpad[OCG + j] * rsqrtf(wpad[OCRV + j] + 1e-5f);
        float t = wpad[OCBB + j] - wpad[OCRM + j] * s;
        float w0 = wpad[OCW2 + j * 2], w1v = wpad[OCW2 + j * 2 + 1];
        w2p[j * 2] = s * w0;
        w2p[j * 2 + 1] = s * w1v;
        float c0 = t * w0, c1 = t * w1v;
#pragma unroll
        for (int off = 1; off < 64; off <<= 1) {
            c0 += __shfl_xor(c0, off);
            c1 += __shfl_xor(c1, off);
        }
        int wv = tid >> 6, lane = tid & 63;
        if (lane == 0) { red[wv * 2] = c0; red[wv * 2 + 1] = c1; }
        __syncthreads();
        if (tid == 0) b2p2[0] = wpad[OCB2] + red[0] + red[2] + red[4] + red[6];
        if (tid == 1) b2p2[1] = wpad[OCB2 + 1] + red[1] + red[3] + red[5] + red[7];
    }
}

// Fold layers 1-3 ChebConv weights into MFMA B-fragment order (bf16).
__global__ __launch_bounds__(256) void k_foldw(const float* __restrict__ wpad,
                                               u16* __restrict__ Wf1,
                                               u16* __restrict__ Wf2, u16* __restrict__ Wf3) {
    int b = blockIdx.x, tid = threadIdx.x;
    const float* src;
    u16* dst;
    if (b < 12)      { src = wpad + OCH1; dst = Wf1; }
    else if (b < 24) { src = wpad + OCH2; dst = Wf2; b -= 12; }
    else             { src = wpad + OCH3; dst = Wf3; b -= 24; }
    int base = b * 1024 + tid * 4;
#pragma unroll
    for (int u = 0; u < 4; u++) {
        int gi = base + u;
        int jj = gi & 7;
        int lane = (gi >> 3) & 63;
        int ct = (gi >> 9) & 3;
        int kt = gi >> 11;
        int k = kt * 32 + ((lane >> 4) & 3) * 8 + jj;
        int col = ct * 16 + (lane & 15);
        dst[gi] = f2bf(src[k * 64 + col]);
    }
}

// Fold layer-0 weights (commuted form): Wg0 = B-fragments of [W1 | W2 | W0-W2].
__global__ __launch_bounds__(256) void k_foldw0(const float* __restrict__ wpad,
                                                u16* __restrict__ Wg0) {
    const float* src = wpad + OCH0;  // [3][128][64]
    int tid = threadIdx.x;
    int base = blockIdx.x * 1024 + tid * 4;
#pragma unroll
    for (int u = 0; u < 4; u++) {
        int gi = base + u;
        int jj = gi & 7;
        int lane = (gi >> 3) & 63;
        int rest = gi >> 9;      // kt*12 + ct
        int ct = rest % 12;
        int kt = rest / 12;
        int k = kt * 32 + ((lane >> 4) & 3) * 8 + jj;
        int cl = (lane & 15);
        float v;
        if (ct < 4) {
            v = src[(1 * 128 + k) * 64 + ct * 16 + cl];                    // W1
        } else if (ct < 8) {
            v = src[(2 * 128 + k) * 64 + (ct - 4) * 16 + cl];              // W2
        } else {
            int c = (ct - 8) * 16 + cl;
            v = src[(0 * 128 + k) * 64 + c] - src[(2 * 128 + k) * 64 + c]; // W0-W2
        }
        Wg0[gi] = f2bf(v);
    }
}

// features (either dtype) -> bf16 X0.
__global__ __launch_bounds__(256) void k_x0(const void* __restrict__ feat, const int* __restrict__ flag,
                                            u16* __restrict__ X0) {
    int i = blockIdx.x * 256 + threadIdx.x;
    if (flag[0] != 0) {
        ((uint4*)X0)[i] = ((const uint4*)feat)[i];
    } else {
        const float4* f = (const float4*)feat;
        float4 a = f[2 * i], b = f[2 * i + 1];
        u16x8 o;
        o[0] = f2bf(a.x); o[1] = f2bf(a.y); o[2] = f2bf(a.z); o[3] = f2bf(a.w);
        o[4] = f2bf(b.x); o[5] = f2bf(b.y); o[6] = f2bf(b.z); o[7] = f2bf(b.w);
        ((uint4*)X0)[i] = __builtin_bit_cast(uint4, o);
    }
}

// PAE, v8: both layers MFMA + packed-f32x2 epilogue (R6/R7).
// Grid back to 4 blocks/CU: R3's 4/CU regression was atomic-bounce at 2x the
// atomic count; R5 halved the atomics (u64 packed, WRITE 112->62MB confirmed).
// Latency-bound kernel (5.4K cyc/group vs ~1.5K issue model) -> occupancy
// 30->40% should pay now. Revert if hbm_bytes grows past ~110MB.
__global__ __launch_bounds__(256, 4) void k_pae(const void* __restrict__ zin, const float* __restrict__ wpad,
                                                const u16* __restrict__ W2sg, const float* __restrict__ b2p,
                                                const int* __restrict__ ei, const int* __restrict__ flag,
                                                float* __restrict__ ewf, void* __restrict__ dout,
                                                u64* __restrict__ dc) {
    __shared__ __align__(16) u16 sW2[16384];
    __shared__ float sB2[128];
    int tid = threadIdx.x;
    for (int i = tid; i < 8192; i += 256) ((u32*)sW2)[i] = ((const u32*)W2sg)[i];
    if (tid < 128) sB2[tid] = b2p[tid];
    __syncthreads();

    bool isbf = flag[0] != 0;
    int wv = __builtin_amdgcn_readfirstlane(tid >> 6);
    int lane = tid & 63;
    int quad = lane >> 4, lrow = lane & 15, jc = lane & 15;
    u32 qm = (quad == 0) ? 0xffffffffu : 0u;  // B-frag mask: only quad 0 supplies z

    // loop-invariant stage-1 operands: W1 A-frags (8 tiles) + b1 C-inits
    uint4 w1f[8];
    f32x4 cb[8];
#pragma unroll
    for (int kt = 0; kt < 8; kt++) {
        u32 a = 0, b = 0, c = 0;
        if (quad == 0) {
            int col = kt * 16 + lrow;
            a = (u32)f2bf(wpad[OW1 + 0 * 128 + col]) | ((u32)f2bf(wpad[OW1 + 1 * 128 + col]) << 16);
            b = (u32)f2bf(wpad[OW1 + 2 * 128 + col]) | ((u32)f2bf(wpad[OW1 + 3 * 128 + col]) << 16);
            c = (u32)f2bf(wpad[OW1 + 4 * 128 + col]) | ((u32)f2bf(wpad[OW1 + 5 * 128 + col]) << 16);
        }
        w1f[kt] = (uint4){a, b, c, 0u};
#pragma unroll
        for (int r = 0; r < 4; r++) cb[kt][r] = wpad[OB1 + kt * 16 + quad * 4 + r];
    }

    int gw = blockIdx.x * 4 + wv;
    const int ngroups = EE / 16;
    const int gstep = gridDim.x * 4;

    uint2 pb0, pb1, pb2;       // bf16 Z prefetch (24B row)
    float4 pf0, pf1, pf2;      // fp32 Z prefetch (48B row)
    if (gw < ngroups) {
        if (isbf) {
            const uint2* zp = (const uint2*)((const u16*)zin + (size_t)(gw * 16 + lrow) * 12);
            pb0 = zp[0]; pb1 = zp[1]; pb2 = zp[2];
        } else {
            const float4* zp = (const float4*)((const float*)zin + (size_t)(gw * 16 + lrow) * 12);
            pf0 = zp[0]; pf1 = zp[1]; pf2 = zp[2];
        }
    }

#pragma unroll 1
    for (int gidx = gw; gidx < ngroups; gidx += gstep) {
        int e0 = gidx * 16;
        float z1[6], z2[6];
        if (isbf) {
            z1[0] = bfl(pb0.x); z1[1] = bfh(pb0.x); z1[2] = bfl(pb0.y); z1[3] = bfh(pb0.y);
            z1[4] = bfl(pb1.x); z1[5] = bfh(pb1.x);
            z2[0] = bfl(pb1.y); z2[1] = bfh(pb1.y); z2[2] = bfl(pb2.x); z2[3] = bfh(pb2.x);
            z2[4] = bfl(pb2.y); z2[5] = bfh(pb2.y);
        } else {
            z1[0] = pf0.x; z1[1] = pf0.y; z1[2] = pf0.z; z1[3] = pf0.w; z1[4] = pf1.x; z1[5] = pf1.y;
            z2[0] = pf1.z; z2[1] = pf1.w; z2[2] = pf2.x; z2[3] = pf2.y; z2[4] = pf2.z; z2[5] = pf2.w;
        }
        // issue next group's Z loads now -- they complete under this group's compute
        int gn = gidx + gstep;
        if (gn < ngroups) {
            if (isbf) {
                const uint2* zp = (const uint2*)((const u16*)zin + (size_t)(gn * 16 + lrow) * 12);
                pb0 = zp[0]; pb1 = zp[1]; pb2 = zp[2];
            } else {
                const float4* zp = (const float4*)((const float*)zin + (size_t)(gn * 16 + lrow) * 12);
                pf0 = zp[0]; pf1 = zp[1]; pf2 = zp[2];
            }
        }
        // hoist epilogue row indices
        int rows[4];
        if (jc == 0) {
#pragma unroll
            for (int r = 0; r < 4; r++) rows[r] = ei[e0 + quad * 4 + r];
        }

        // build z B-frags (quad 0 only; lossless round-trip for bf16 inputs)
        u32 za0, za1, za2, zb0, zb1, zb2;
        asm("v_cvt_pk_bf16_f32 %0, %1, %2" : "=v"(za0) : "v"(z1[0]), "v"(z1[1]));
        asm("v_cvt_pk_bf16_f32 %0, %1, %2" : "=v"(za1) : "v"(z1[2]), "v"(z1[3]));
        asm("v_cvt_pk_bf16_f32 %0, %1, %2" : "=v"(za2) : "v"(z1[4]), "v"(z1[5]));
        asm("v_cvt_pk_bf16_f32 %0, %1, %2" : "=v"(zb0) : "v"(z2[0]), "v"(z2[1]));
        asm("v_cvt_pk_bf16_f32 %0, %1, %2" : "=v"(zb1) : "v"(z2[2]), "v"(z2[3]));
        asm("v_cvt_pk_bf16_f32 %0, %1, %2" : "=v"(zb2) : "v"(z2[4]), "v"(z2[5]));
        uint4 zu1 = {za0 & qm, za1 & qm, za2 & qm, 0u};
        uint4 zu2 = {zb0 & qm, zb1 & qm, zb2 & qm, 0u};
        bf16x8 zf1 = __builtin_bit_cast(bf16x8, zu1);
        bf16x8 zf2 = __builtin_bit_cast(bf16x8, zu2);

        // stage 1 + pack, encoding 1
        bf16x8 a1f[4], a2f[4];
        {
            f32x4 c1[8];
#pragma unroll
            for (int kt = 0; kt < 8; kt++)
                c1[kt] = __builtin_amdgcn_mfma_f32_16x16x32_bf16(
                    __builtin_bit_cast(bf16x8, w1f[kt]), zf1, cb[kt], 0, 0, 0);
#pragma unroll
            for (int kc = 0; kc < 4; kc++) {
                float h0 = fmaxf(c1[2 * kc][0], 0.f), h1 = fmaxf(c1[2 * kc][1], 0.f);
                float h2 = fmaxf(c1[2 * kc][2], 0.f), h3 = fmaxf(c1[2 * kc][3], 0.f);
                float h4 = fmaxf(c1[2 * kc + 1][0], 0.f), h5 = fmaxf(c1[2 * kc + 1][1], 0.f);
                float h6 = fmaxf(c1[2 * kc + 1][2], 0.f), h7 = fmaxf(c1[2 * kc + 1][3], 0.f);
                u32 p0, p1, p2, p3;
                asm("v_cvt_pk_bf16_f32 %0, %1, %2" : "=v"(p0) : "v"(h0), "v"(h1));
                asm("v_cvt_pk_bf16_f32 %0, %1, %2" : "=v"(p1) : "v"(h2), "v"(h3));
                asm("v_cvt_pk_bf16_f32 %0, %1, %2" : "=v"(p2) : "v"(h4), "v"(h5));
                asm("v_cvt_pk_bf16_f32 %0, %1, %2" : "=v"(p3) : "v"(h6), "v"(h7));
                uint4 au = {p0, p1, p2, p3};
                a1f[kc] = __builtin_bit_cast(bf16x8, au);
            }
        }
        // stage 1 + pack, encoding 2
        {
            f32x4 c2[8];
#pragma unroll
            for (int kt = 0; kt < 8; kt++)
                c2[kt] = __builtin_amdgcn_mfma_f32_16x16x32_bf16(
                    __builtin_bit_cast(bf16x8, w1f[kt]), zf2, cb[kt], 0, 0, 0);
#pragma unroll
            for (int kc = 0; kc < 4; kc++) {
                float h0 = fmaxf(c2[2 * kc][0], 0.f), h1 = fmaxf(c2[2 * kc][1], 0.f);
                float h2 = fmaxf(c2[2 * kc][2], 0.f), h3 = fmaxf(c2[2 * kc][3], 0.f);
                float h4 = fmaxf(c2[2 * kc + 1][0], 0.f), h5 = fmaxf(c2[2 * kc + 1][1], 0.f);
                float h6 = fmaxf(c2[2 * kc + 1][2], 0.f), h7 = fmaxf(c2[2 * kc + 1][3], 0.f);
                u32 p0, p1, p2, p3;
                asm("v_cvt_pk_bf16_f32 %0, %1, %2" : "=v"(p0) : "v"(h0), "v"(h1));
                asm("v_cvt_pk_bf16_f32 %0, %1, %2" : "=v"(p1) : "v"(h2), "v"(h3));
                asm("v_cvt_pk_bf16_f32 %0, %1, %2" : "=v"(p2) : "v"(h4), "v"(h5));
                asm("v_cvt_pk_bf16_f32 %0, %1, %2" : "=v"(p3) : "v"(h6), "v"(h7));
                uint4 au = {p0, p1, p2, p3};
                a2f[kc] = __builtin_bit_cast(bf16x8, au);
            }
        }

        // packed cosine accumulators: 6 independent f32x2 chains
        f32x2 numA = {0.f, 0.f}, numB = {0.f, 0.f};
        f32x2 q1A = {0.f, 0.f}, q1B = {0.f, 0.f};
        f32x2 q2A = {0.f, 0.f}, q2B = {0.f, 0.f};
        // jt NOT unrolled: keeps ds_read hoisting bounded (spill guard).
#pragma unroll 1
        for (int jt = 0; jt < 8; jt++) {
            f32x4 acc1 = {0.f, 0.f, 0.f, 0.f}, acc2 = {0.f, 0.f, 0.f, 0.f};
#pragma unroll
            for (int kc = 0; kc < 4; kc++) {
                bf16x8 bb = *reinterpret_cast<const bf16x8*>(&sW2[((kc * 8 + jt) * 64 + lane) * 8]);
                acc1 = __builtin_amdgcn_mfma_f32_16x16x32_bf16(a1f[kc], bb, acc1, 0, 0, 0);
                acc2 = __builtin_amdgcn_mfma_f32_16x16x32_bf16(a2f[kc], bb, acc2, 0, 0, 0);
            }
            float bbias = sB2[jt * 16 + jc];
            f32x2 bb2 = {bbias, bbias};
            f32x2 a1lo = {acc1[0], acc1[1]}, a1hi = {acc1[2], acc1[3]};
            f32x2 a2lo = {acc2[0], acc2[1]}, a2hi = {acc2[2], acc2[3]};
            f32x2 h1A, h1B, h2A, h2B;
            asm("v_pk_add_f32 %0, %1, %2" : "=v"(h1A) : "v"(a1lo), "v"(bb2));
            asm("v_pk_add_f32 %0, %1, %2" : "=v"(h1B) : "v"(a1hi), "v"(bb2));
            asm("v_pk_add_f32 %0, %1, %2" : "=v"(h2A) : "v"(a2lo), "v"(bb2));
            asm("v_pk_add_f32 %0, %1, %2" : "=v"(h2B) : "v"(a2hi), "v"(bb2));
            asm("v_pk_fma_f32 %0, %1, %2, %0" : "+v"(numA) : "v"(h1A), "v"(h2A));
            asm("v_pk_fma_f32 %0, %1, %2, %0" : "+v"(numB) : "v"(h1B), "v"(h2B));
            asm("v_pk_fma_f32 %0, %1, %2, %0" : "+v"(q1A) : "v"(h1A), "v"(h1A));
            asm("v_pk_fma_f32 %0, %1, %2, %0" : "+v"(q1B) : "v"(h1B), "v"(h1B));
            asm("v_pk_fma_f32 %0, %1, %2, %0" : "+v"(q2A) : "v"(h2A), "v"(h2A));
            asm("v_pk_fma_f32 %0, %1, %2, %0" : "+v"(q2B) : "v"(h2B), "v"(h2B));
        }
        float num[4] = {numA[0], numA[1], numB[0], numB[1]};
        float q1[4] = {q1A[0], q1A[1], q1B[0], q1B[1]};
        float q2[4] = {q2A[0], q2A[1], q2B[0], q2B[1]};
#pragma unroll
        for (int off = 1; off < 16; off <<= 1) {
#pragma unroll
            for (int r = 0; r < 4; r++) {
                num[r] += __shfl_xor(num[r], off);
                q1[r] += __shfl_xor(q1[r], off);
                q2[r] += __shfl_xor(q2[r], off);
            }
        }
        if (jc == 0) {
#pragma unroll
            for (int r = 0; r < 4; r++) {
                int e = e0 + quad * 4 + r;
                float den = fmaxf(sqrtf(q1[r]) * sqrtf(q2[r]), 1e-8f);
                float wgt = (num[r] / den + 1.f) * 0.5f;
                if (!(wgt == wgt)) wgt = 0.5f;  // NaN guard: makes failures localizable
                ewf[e] = wgt;
                if (isbf) ((u16*)dout)[EW_OFF + e] = f2bf(wgt);
                else ((float*)dout)[EW_OFF + e] = wgt;
                // one u64 atomic: hi32 = count(+1), lo32 = wgt in 8.23 fixed point
                u32 fx = (u32)(wgt * 8388608.f + 0.5f);
                atomicAdd(dc + rows[r], (((u64)1) << 32) | (u64)fx);
            }
        }
    }
}

// Exclusive scan of cnt (hi32 of dc) -> offs; fused dis = rsqrt(deg).
__global__ __launch_bounds__(1024) void k_scan(const u64* __restrict__ dc,
                                               int* __restrict__ offs, float* __restrict__ dis) {
    __shared__ int wsum[16];
    __shared__ int carry;
    int tid = threadIdx.x;
    int wv = tid >> 6, lane = tid & 63;
    if (tid == 0) carry = 0;
    __syncthreads();
    for (int c = 0; c < 49; c++) {
        int i = c * 1024 + tid;
        u64 v64 = (i < NN) ? dc[i] : 0ull;
        int v = (int)(v64 >> 32);
        if (i < NN) {
            float d = (float)(u32)v64 * (1.f / 8388608.f);
            dis[i] = d > 0.f ? rsqrtf(d) : 0.f;
        }
        int x = v;
#pragma unroll
        for (int off = 1; off < 64; off <<= 1) {
            int t = __shfl_up(x, off);
            if (lane >= off) x += t;
        }
        if (lane == 63) wsum[wv] = x;
        __syncthreads();
        if (tid < 16) {
            int s = wsum[tid];
#pragma unroll
            for (int off = 1; off < 16; off <<= 1) {
                int t = __shfl_up(s, off, 16);
                if (tid >= off) s += t;
            }
            wsum[tid] = s;
        }
        __syncthreads();
        int base = carry + (wv > 0 ? wsum[wv - 1] : 0);
        if (i < NN) offs[i] = base + x - v;
        __syncthreads();
        if (tid == 0) carry += wsum[15];
        __syncthreads();
    }
    if (tid == 0) offs[NN] = carry;
}

// CSR scatter: fused (col, norm) uint2 metadata — one 8B load per edge in prop.
__global__ __launch_bounds__(256) void k_csr(const int* __restrict__ ei, const float* __restrict__ ewf,
                                             const float* __restrict__ dis, const int* __restrict__ offs,
                                             int* __restrict__ cursor, uint2* __restrict__ csr_meta) {
    int e = blockIdx.x * 256 + threadIdx.x;
    int r = ei[e], c = ei[EE + e];
    float wgt = ewf[e];
    int pos = offs[r] + atomicAdd(cursor + r, 1);
    float nrm = -dis[r] * wgt * dis[c];
    csr_meta[pos] = make_uint2((u32)c, __builtin_bit_cast(u32, nrm));
}

// ---- propagation kernels (R7: masked full-width tails, no serial loops) ----
// Masked lanes clamp meta index to e-1 (all masked lanes hit the SAME row ->
// L1 broadcast) and use weight 0, so the dependent serial tail (8/64 lanes,
// up to 7 gather-latency-bound iterations per node) disappears.

// Layer-0 first prop: 128-wide gather of U, output SPLIT into compact V1/V2
// (N x 64 each) so the second prop's gather fetches 128B rows, not 256B spans.
__global__ __launch_bounds__(256) void k_prop0a(const u16* __restrict__ U, const uint2* __restrict__ csr_meta,
                                                const int* __restrict__ offs,
                                                u16* __restrict__ V1, u16* __restrict__ V2) {
    int lane = threadIdx.x & 63;
    int wv = threadIdx.x >> 6;
    int node = blockIdx.x * 4 + wv;
    int s = offs[node], e = offs[node + 1];
    int sub = lane >> 4;
    int fl = lane & 15;
    const uint4* sv = (const uint4*)U;  // row = 16 uint4 (128 bf16)
    float a[8] = {0, 0, 0, 0, 0, 0, 0, 0};
    int p = s;
    if (p < e) {
        int i0 = p + sub, i1 = p + 4 + sub;
        uint2 m0 = csr_meta[min(i0, e - 1)];
        uint2 m1 = csr_meta[min(i1, e - 1)];
        float w0 = (i0 < e) ? __builtin_bit_cast(float, m0.y) : 0.f;
        float w1 = (i1 < e) ? __builtin_bit_cast(float, m1.y) : 0.f;
        while (true) {
            uint4 v0 = sv[(size_t)m0.x * 16 + fl];
            uint4 v1 = sv[(size_t)m1.x * 16 + fl];
            float w0c = w0, w1c = w1;
            p += 8;
            bool more = p < e;
            if (more) {
                i0 = p + sub; i1 = p + 4 + sub;
                m0 = csr_meta[min(i0, e - 1)];
                m1 = csr_meta[min(i1, e - 1)];
                w0 = (i0 < e) ? __builtin_bit_cast(float, m0.y) : 0.f;
                w1 = (i1 < e) ? __builtin_bit_cast(float, m1.y) : 0.f;
            }
            a[0] = fmaf(w0c, bfl(v0.x), a[0]); a[1] = fmaf(w0c, bfh(v0.x), a[1]);
            a[2] = fmaf(w0c, bfl(v0.y), a[2]); a[3] = fmaf(w0c, bfh(v0.y), a[3]);
            a[4] = fmaf(w0c, bfl(v0.z), a[4]); a[5] = fmaf(w0c, bfh(v0.z), a[5]);
            a[6] = fmaf(w0c, bfl(v0.w), a[6]); a[7] = fmaf(w0c, bfh(v0.w), a[7]);
            a[0] = fmaf(w1c, bfl(v1.x), a[0]); a[1] = fmaf(w1c, bfh(v1.x), a[1]);
            a[2] = fmaf(w1c, bfl(v1.y), a[2]); a[3] = fmaf(w1c, bfh(v1.y), a[3]);
            a[4] = fmaf(w1c, bfl(v1.z), a[4]); a[5] = fmaf(w1c, bfh(v1.z), a[5]);
            a[6] = fmaf(w1c, bfl(v1.w), a[6]); a[7] = fmaf(w1c, bfh(v1.w), a[7]);
            if (!more) break;
        }
    }
#pragma unroll
    for (int i = 0; i < 8; i++) {
        a[i] += __shfl_xor(a[i], 16);
        a[i] += __shfl_xor(a[i], 32);
    }
    if (sub == 0) {
        uint4 ov;
        ov.x = (u32)f2bf(a[0]) | ((u32)f2bf(a[1]) << 16);
        ov.y = (u32)f2bf(a[2]) | ((u32)f2bf(a[3]) << 16);
        ov.z = (u32)f2bf(a[4]) | ((u32)f2bf(a[5]) << 16);
        ov.w = (u32)f2bf(a[6]) | ((u32)f2bf(a[7]) << 16);
        if (fl < 8) ((uint4*)V1)[(size_t)node * 8 + fl] = ov;
        else ((uint4*)V2)[(size_t)node * 8 + (fl - 8)] = ov;
    }
}

// Layer-0 second prop: gathers COMPACT V2 (N x 64), fuses combine
// h0 = relu(D + V1 + 2*S); writes h0 (bf16) and jk slice 0.
__global__ __launch_bounds__(256) void k_prop0b(const u16* __restrict__ V1, const u16* __restrict__ V2,
                                                const uint2* __restrict__ csr_meta,
                                                const int* __restrict__ offs, const u16* __restrict__ D,
                                                u16* __restrict__ h0out, const int* __restrict__ flag,
                                                void* __restrict__ jkout) {
    int lane = threadIdx.x & 63;
    int wv = threadIdx.x >> 6;
    int node = blockIdx.x * 4 + wv;
    int s = offs[node], e = offs[node + 1];
    int sub = lane >> 3;
    int fl = lane & 7;
    const uint4* sv = (const uint4*)V2;  // row = 8 uint4 (64 bf16)
    float a[8] = {0, 0, 0, 0, 0, 0, 0, 0};
    int p = s;
    if (p < e) {
        int i0 = p + sub, i1 = p + 8 + sub;
        uint2 m0 = csr_meta[min(i0, e - 1)];
        uint2 m1 = csr_meta[min(i1, e - 1)];
        float w0 = (i0 < e) ? __builtin_bit_cast(float, m0.y) : 0.f;
        float w1 = (i1 < e) ? __builtin_bit_cast(float, m1.y) : 0.f;
        while (true) {
            uint4 v0 = sv[(size_t)m0.x * 8 + fl];
            uint4 v1 = sv[(size_t)m1.x * 8 + fl];
            float w0c = w0, w1c = w1;
            p += 16;
            bool more = p < e;
            if (more) {
                i0 = p + sub; i1 = p + 8 + sub;
                m0 = csr_meta[min(i0, e - 1)];
                m1 = csr_meta[min(i1, e - 1)];
                w0 = (i0 < e) ? __builtin_bit_cast(float, m0.y) : 0.f;
                w1 = (i1 < e) ? __builtin_bit_cast(float, m1.y) : 0.f;
            }
            a[0] = fmaf(w0c, bfl(v0.x), a[0]); a[1] = fmaf(w0c, bfh(v0.x), a[1]);
            a[2] = fmaf(w0c, bfl(v0.y), a[2]); a[3] = fmaf(w0c, bfh(v0.y), a[3]);
            a[4] = fmaf(w0c, bfl(v0.z), a[4]); a[5] = fmaf(w0c, bfh(v0.z), a[5]);
            a[6] = fmaf(w0c, bfl(v0.w), a[6]); a[7] = fmaf(w0c, bfh(v0.w), a[7]);
            a[0] = fmaf(w1c, bfl(v1.x), a[0]); a[1] = fmaf(w1c, bfh(v1.x), a[1]);
            a[2] = fmaf(w1c, bfl(v1.y), a[2]); a[3] = fmaf(w1c, bfh(v1.y), a[3]);
            a[4] = fmaf(w1c, bfl(v1.z), a[4]); a[5] = fmaf(w1c, bfh(v1.z), a[5]);
            a[6] = fmaf(w1c, bfl(v1.w), a[6]); a[7] = fmaf(w1c, bfh(v1.w), a[7]);
            if (!more) break;
        }
    }
#pragma unroll
    for (int i = 0; i < 8; i++) {
        a[i] += __shfl_xor(a[i], 8);
        a[i] += __shfl_xor(a[i], 16);
        a[i] += __shfl_xor(a[i], 32);
    }
    if (sub == 0) {
        uint4 v1 = ((const uint4*)V1)[(size_t)node * 8 + fl];
        uint4 dv = ((const uint4*)D)[(size_t)node * 8 + fl];
        float o[8];
        o[0] = fmaf(2.f, a[0], bfl(v1.x) + bfl(dv.x)); o[1] = fmaf(2.f, a[1], bfh(v1.x) + bfh(dv.x));
        o[2] = fmaf(2.f, a[2], bfl(v1.y) + bfl(dv.y)); o[3] = fmaf(2.f, a[3], bfh(v1.y) + bfh(dv.y));
        o[4] = fmaf(2.f, a[4], bfl(v1.z) + bfl(dv.z)); o[5] = fmaf(2.f, a[5], bfh(v1.z) + bfh(dv.z));
        o[6] = fmaf(2.f, a[6], bfl(v1.w) + bfl(dv.w)); o[7] = fmaf(2.f, a[7], bfh(v1.w) + bfh(dv.w));
#pragma unroll
        for (int i = 0; i < 8; i++) o[i] = fmaxf(o[i], 0.f);
        uint4 ov;
        ov.x = (u32)f2bf(o[0]) | ((u32)f2bf(o[1]) << 16);
        ov.y = (u32)f2bf(o[2]) | ((u32)f2bf(o[3]) << 16);
        ov.z = (u32)f2bf(o[4]) | ((u32)f2bf(o[5]) << 16);
        ov.w = (u32)f2bf(o[6]) | ((u32)f2bf(o[7]) << 16);
        ((uint4*)h0out)[(size_t)node * 8 + fl] = ov;
        if (flag[0] != 0) {
            ((uint4*)jkout)[(size_t)node * 32 + fl] = ov;  // jk row = 32 uint4, slice 0
        } else {
            float* jf = (float*)jkout + (size_t)node * 256 + fl * 8;
#pragma unroll
            for (int i = 0; i < 8; i++) jf[i] = o[i];
        }
    }
}

// Layers 1-3 propagation: 64-wide gather, masked tail, alpha/beta epilogue.
__global__ __launch_bounds__(256) void k_prop64(const u16* __restrict__ src, const uint2* __restrict__ csr_meta,
                                                const int* __restrict__ offs,
                                                u16* __restrict__ out, const u16* __restrict__ base,
                                                float alpha, float beta) {
    int lane = threadIdx.x & 63;
    int wv = threadIdx.x >> 6;
    int node = blockIdx.x * 4 + wv;
    int s = offs[node], e = offs[node + 1];
    int sub = lane >> 3;
    int fl = lane & 7;
    const uint4* sv = (const uint4*)src;  // row = 8 uint4 (64 bf16)
    float a[8] = {0, 0, 0, 0, 0, 0, 0, 0};
    int p = s;
    if (p < e) {
        int i0 = p + sub, i1 = p + 8 + sub;
        uint2 m0 = csr_meta[min(i0, e - 1)];
        uint2 m1 = csr_meta[min(i1, e - 1)];
        float w0 = (i0 < e) ? __builtin_bit_cast(float, m0.y) : 0.f;
        float w1 = (i1 < e) ? __builtin_bit_cast(float, m1.y) : 0.f;
        while (true) {
            uint4 v0 = sv[(size_t)m0.x * 8 + fl];
            uint4 v1 = sv[(size_t)m1.x * 8 + fl];
            float w0c = w0, w1c = w1;
            p += 16;
            bool more = p < e;
            if (more) {
                i0 = p + sub; i1 = p + 8 + sub;
                m0 = csr_meta[min(i0, e - 1)];
                m1 = csr_meta[min(i1, e - 1)];
                w0 = (i0 < e) ? __builtin_bit_cast(float, m0.y) : 0.f;
                w1 = (i1 < e) ? __builtin_bit_cast(float, m1.y) : 0.f;
            }
            a[0] = fmaf(w0c, bfl(v0.x), a[0]); a[1] = fmaf(w0c, bfh(v0.x), a[1]);
            a[2] = fmaf(w0c, bfl(v0.y), a[2]); a[3] = fmaf(w0c, bfh(v0.y), a[3]);
            a[4] = fmaf(w0c, bfl(v0.z), a[4]); a[5] = fmaf(w0c, bfh(v0.z), a[5]);
            a[6] = fmaf(w0c, bfl(v0.w), a[6]); a[7] = fmaf(w0c, bfh(v0.w), a[7]);
            a[0] = fmaf(w1c, bfl(v1.x), a[0]); a[1] = fmaf(w1c, bfh(v1.x), a[1]);
            a[2] = fmaf(w1c, bfl(v1.y), a[2]); a[3] = fmaf(w1c, bfh(v1.y), a[3]);
            a[4] = fmaf(w1c, bfl(v1.z), a[4]); a[5] = fmaf(w1c, bfh(v1.z), a[5]);
            a[6] = fmaf(w1c, bfl(v1.w), a[6]); a[7] = fmaf(w1c, bfh(v1.w), a[7]);
            if (!more) break;
        }
    }
#pragma unroll
    for (int i = 0; i < 8; i++) {
        a[i] += __shfl_xor(a[i], 8);
        a[i] += __shfl_xor(a[i], 16);
        a[i] += __shfl_xor(a[i], 32);
    }
    if (sub == 0) {
        float o[8];
#pragma unroll
        for (int i = 0; i < 8; i++) o[i] = alpha * a[i];
        if (beta != 0.f) {
            uint4 bv = ((const uint4*)base)[(size_t)node * 8 + fl];
            o[0] = fmaf(beta, bfl(bv.x), o[0]); o[1] = fmaf(beta, bfh(bv.x), o[1]);
            o[2] = fmaf(beta, bfl(bv.y), o[2]); o[3] = fmaf(beta, bfh(bv.y), o[3]);
            o[4] = fmaf(beta, bfl(bv.z), o[4]); o[5] = fmaf(beta, bfh(bv.z), o[5]);
            o[6] = fmaf(beta, bfl(bv.w), o[6]); o[7] = fmaf(beta, bfh(bv.w), o[7]);
        }
        uint4 ov;
        ov.x = (u32)f2bf(o[0]) | ((u32)f2bf(o[1]) << 16);
        ov.y = (u32)f2bf(o[2]) | ((u32)f2bf(o[3]) << 16);
        ov.z = (u32)f2bf(o[4]) | ((u32)f2bf(o[5]) << 16);
        ov.w = (u32)f2bf(o[6]) | ((u32)f2bf(o[7]) << 16);
        ((uint4*)out)[(size_t)node * 8 + fl] = ov;
    }
}

// Layer-0 projection gemm (commuted form): G = X @ [W1 | W2 | W0-W2],
// cols 0..127 -> U (N x 128), cols 128..191 -> D (N x 64). No relu.
__global__ __launch_bounds__(256) void k_gemm0(const u16* __restrict__ X0, const u16* __restrict__ Wg0,
                                               u16* __restrict__ U, u16* __restrict__ D) {
    __shared__ __align__(16) u16 sB[4 * 12 * 64 * 8];  // 48KB
    int tid = threadIdx.x;
    for (int i = tid; i < 12288; i += 256) ((u32*)sB)[i] = ((const u32*)Wg0)[i];
    __syncthreads();

    int wv = __builtin_amdgcn_readfirstlane(tid >> 6);
    int lane = tid & 63;
    int quad = lane >> 4, jc = lane & 15;
    int pair = wv >> 1;   // row group
    int half = wv & 1;    // column half (96 cols each)
    int nb = blockIdx.x * 32 + pair * 16;
    int row = nb + jc;
    if (row > NN - 1) row = NN - 1;

    uint4 av[4];
#pragma unroll
    for (int kt = 0; kt < 4; kt++)
        av[kt] = *(const uint4*)(X0 + (size_t)row * 128 + kt * 32 + quad * 8);

    f32x4 acc[6] = {{0.f, 0.f, 0.f, 0.f}, {0.f, 0.f, 0.f, 0.f}, {0.f, 0.f, 0.f, 0.f},
                    {0.f, 0.f, 0.f, 0.f}, {0.f, 0.f, 0.f, 0.f}, {0.f, 0.f, 0.f, 0.f}};
#pragma unroll
    for (int kt = 0; kt < 4; kt++) {
        bf16x8 af = __builtin_bit_cast(bf16x8, av[kt]);
#pragma unroll
        for (int ct = 0; ct < 6; ct++) {
            int g = half * 6 + ct;
            bf16x8 b0 = *reinterpret_cast<const bf16x8*>(&sB[((kt * 12 + g) * 64 + lane) * 8]);
            acc[ct] = __builtin_amdgcn_mfma_f32_16x16x32_bf16(af, b0, acc[ct], 0, 0, 0);
        }
    }

#pragma unroll
    for (int ct = 0; ct < 6; ct++) {
        int g = half * 6 + ct;
        int j = g * 16 + jc;
#pragma unroll
        for (int r = 0; r < 4; r++) {
            int n = nb + quad * 4 + r;
            if (n < NN) {
                float v = acc[ct][r];
                if (j < 128) U[(size_t)n * 128 + j] = f2bf(v);
                else D[(size_t)n * 64 + (j - 128)] = f2bf(v);
            }
        }
    }
}

// ChebConv mix via MFMA -> bf16 h + jk slice (out dtype). Layers 1-3 (F=64).
template <int F>
__global__ __launch_bounds__(256) void k_gemm(const u16* __restrict__ X0, const u16* __restrict__ X1,
                                              const u16* __restrict__ X2, const u16* __restrict__ Wf,
                                              u16* __restrict__ Hout, void* __restrict__ jk, int jkoff,
                                              const int* __restrict__ flag) {
    constexpr int KT = (3 * F) / 32;  // 6 (F=64)
    __shared__ __align__(16) u16 sB[KT * 4 * 64 * 8];
    int tid = threadIdx.x;
    for (int i = tid; i < KT * 4 * 64 * 4; i += 256) ((u32*)sB)[i] = ((const u32*)Wf)[i];
    __syncthreads();

    bool isbf = flag[0] != 0;
    int wv = __builtin_amdgcn_readfirstlane(tid >> 6);
    int lane = tid & 63;
    int quad = lane >> 4, jc = lane & 15;
    int pair = wv >> 1;   // row group
    int half = wv & 1;    // column half (32 cols)
    int nb = blockIdx.x * 32 + pair * 16;
    int row = nb + jc;
    if (row > NN - 1) row = NN - 1;

    uint4 av[KT];
#pragma unroll
    for (int kt = 0; kt < KT; kt++) {
        int kg = kt * 32 + quad * 8;
        const u16* Xp;
        int kk;
        if (kg < F) { Xp = X0; kk = kg; }
        else if (kg < 2 * F) { Xp = X1; kk = kg - F; }
        else { Xp = X2; kk = kg - 2 * F; }
        av[kt] = *(const uint4*)(Xp + (size_t)row * F + kk);
    }

    f32x4 acc0 = {0.f, 0.f, 0.f, 0.f}, acc1 = {0.f, 0.f, 0.f, 0.f};
#pragma unroll
    for (int kt = 0; kt < KT; kt++) {
        bf16x8 af = __builtin_bit_cast(bf16x8, av[kt]);
        bf16x8 b0 = *reinterpret_cast<const bf16x8*>(&sB[((kt * 4 + half * 2 + 0) * 64 + lane) * 8]);
        bf16x8 b1 = *reinterpret_cast<const bf16x8*>(&sB[((kt * 4 + half * 2 + 1) * 64 + lane) * 8]);
        acc0 = __builtin_amdgcn_mfma_f32_16x16x32_bf16(af, b0, acc0, 0, 0, 0);
        acc1 = __builtin_amdgcn_mfma_f32_16x16x32_bf16(af, b1, acc1, 0, 0, 0);
    }

#pragma unroll
    for (int ct = 0; ct < 2; ct++) {
        f32x4 a = ct ? acc1 : acc0;
        int j = (half * 2 + ct) * 16 + jc;
#pragma unroll
        for (int r = 0; r < 4; r++) {
            int n = nb + quad * 4 + r;
            if (n < NN) {
                float v = fmaxf(a[r], 0.f);
                Hout[(size_t)n * 64 + j] = f2bf(v);
                if (isbf) ((u16*)jk)[(size_t)n * 256 + jkoff + j] = f2bf(v);
                else ((float*)jk)[(size_t)n * 256 + jkoff + j] = v;
            }
        }
    }
}

// Fused classifier: logit = (relu(jk@W1+b1)*s+t)@w2 + b2, z never materialized.
__global__ __launch_bounds__(256) void k_cls(const u16* __restrict__ h0, const u16* __restrict__ h1,
                                             const u16* __restrict__ h2, const u16* __restrict__ h3,
                                             const u16* __restrict__ W1c, const float* __restrict__ wpad,
                                             const float* __restrict__ w2p, const float* __restrict__ b2p2,
                                             const int* __restrict__ flag, void* __restrict__ dout) {
    __shared__ __align__(16) u16 sB[16384];  // one phase slice of W1c (32KB)
    __shared__ float sb1[256];
    __shared__ float sw2[512];
    __shared__ float sb2[2];
    __shared__ float part[4][16][2];
    int tid = threadIdx.x;
    if (tid < 256) sb1[tid] = wpad[OCB1 + tid];
    for (int i = tid; i < 512; i += 256) sw2[i] = w2p[i];
    if (tid < 2) sb2[tid] = b2p2[tid];

    int wv = __builtin_amdgcn_readfirstlane(tid >> 6);
    int lane = tid & 63;
    int quad = lane >> 4, jc = lane & 15;
    int pair = wv >> 1;      // row group (0/1)
    int half = wv & 1;       // column half (0/1)
    int nb = blockIdx.x * 32 + pair * 16;

    f32x4 acc[8] = {{0.f, 0.f, 0.f, 0.f}, {0.f, 0.f, 0.f, 0.f}, {0.f, 0.f, 0.f, 0.f}, {0.f, 0.f, 0.f, 0.f},
                    {0.f, 0.f, 0.f, 0.f}, {0.f, 0.f, 0.f, 0.f}, {0.f, 0.f, 0.f, 0.f}, {0.f, 0.f, 0.f, 0.f}};
    const u16* hs[4] = {h0, h1, h2, h3};

    int row = nb + jc;
    if (row > NN - 1) row = NN - 1;

#pragma unroll 1
    for (int l = 0; l < 4; l++) {
        __syncthreads();
        const u32* src = (const u32*)W1c + l * 8192;
        for (int i = tid; i < 8192; i += 256) ((u32*)sB)[i] = src[i];
        __syncthreads();
        const uint4* rp = (const uint4*)(hs[l] + (size_t)row * 64);
        uint4 a0u = rp[quad], a1u = rp[4 + quad];
        bf16x8 af0 = __builtin_bit_cast(bf16x8, a0u);
        bf16x8 af1 = __builtin_bit_cast(bf16x8, a1u);
#pragma unroll
        for (int jt = 0; jt < 8; jt++) {
            int ct = half * 8 + jt;
            bf16x8 b0 = *reinterpret_cast<const bf16x8*>(&sB[((0 * 16 + ct) * 64 + lane) * 8]);
            bf16x8 b1f = *reinterpret_cast<const bf16x8*>(&sB[((1 * 16 + ct) * 64 + lane) * 8]);
            acc[jt] = __builtin_amdgcn_mfma_f32_16x16x32_bf16(af0, b0, acc[jt], 0, 0, 0);
            acc[jt] = __builtin_amdgcn_mfma_f32_16x16x32_bf16(af1, b1f, acc[jt], 0, 0, 0);
        }
    }

    // epilogue: relu(acc+b1) dot w2' -> per-row logit partials
    float p0[4] = {0, 0, 0, 0}, p1[4] = {0, 0, 0, 0};
#pragma unroll
    for (int jt = 0; jt < 8; jt++) {
        int j = (half * 8 + jt) * 16 + jc;
        float b1v = sb1[j], wa = sw2[2 * j], wb = sw2[2 * j + 1];
#pragma unroll
        for (int r = 0; r < 4; r++) {
            float h = fmaxf(acc[jt][r] + b1v, 0.f);
            p0[r] = fmaf(h, wa, p0[r]);
            p1[r] = fmaf(h, wb, p1[r]);
        }
    }
#pragma unroll
    for (int off = 1; off < 16; off <<= 1) {
#pragma unroll
        for (int r = 0; r < 4; r++) {
            p0[r] += __shfl_xor(p0[r], off);
            p1[r] += __shfl_xor(p1[r], off);
        }
    }
    if (jc == 0) {
#pragma unroll
        for (int r = 0; r < 4; r++) {
            part[wv][quad * 4 + r][0] = p0[r];
            part[wv][quad * 4 + r][1] = p1[r];
        }
    }
    __syncthreads();
    if (tid < 32) {
        int rl = tid & 15, p = tid >> 4;
        int n = blockIdx.x * 32 + tid;
        if (n < NN) {
            float l0 = part[2 * p][rl][0] + part[2 * p + 1][rl][0] + sb2[0];
            float l1 = part[2 * p][rl][1] + part[2 * p + 1][rl][1] + sb2[1];
            if (flag[0] != 0) {
                u32 pack = (u32)f2bf(l0) | ((u32)f2bf(l1) << 16);
                *(u32*)((u16*)dout + LG_OFF + (size_t)n * 2) = pack;
            } else {
                float2 o = {l0, l1};
                *(float2*)((float*)dout + LG_OFF + (size_t)n * 2) = o;
            }
        }
    }
}

extern "C" void kernel_launch(void* const* d_in, const int* in_sizes, int n_in,
                              void* d_out, int out_size, void* d_ws, size_t ws_size,
                              hipStream_t stream) {
    const void* features = d_in[0];
    const int* ei = (const int*)d_in[1];
    const void* zin = d_in[2];

    char* w = (char*)d_ws;
    auto alloc = [&](size_t bytes) -> void* {
        void* p = (void*)w;
        w += (bytes + 255) & ~(size_t)255;
        return p;
    };
    u16* X0 = (u16*)alloc((size_t)NN * 128 * 2);
    u16* Tx1 = (u16*)alloc((size_t)NN * 128 * 2);   // layer0: U; layers1-3: Tx1 (64-wide)
    u16* Tx2 = (u16*)alloc((size_t)NN * 128 * 2);   // layer0: V1|V2 compact; layers1-3: Tx2
    u16* h0 = (u16*)alloc((size_t)NN * 64 * 2);
    u16* h1 = (u16*)alloc((size_t)NN * 64 * 2);
    u16* h2 = (u16*)alloc((size_t)NN * 64 * 2);
    u16* h3 = (u16*)alloc((size_t)NN * 64 * 2);
    u16* Dbuf = (u16*)alloc((size_t)NN * 64 * 2);   // layer0: D = X@(W0-W2)
    float* ewf = (float*)alloc((size_t)EE * 4);
    uint2* csr_meta = (uint2*)alloc((size_t)EE * 8);
    u64* dc = (u64*)alloc((size_t)NN * 8);       // packed (cnt<<32 | deg fixed-point)
    int* cursor = (int*)alloc((size_t)NN * 4);
    float* dis = (float*)alloc((size_t)NN * 4);
    int* offs = (int*)alloc((size_t)(NN + 1) * 4);
    u16* W2s = (u16*)alloc((size_t)16384 * 2);
    float* b2p = (float*)alloc((size_t)128 * 4);
    u16* W1c = (u16*)alloc((size_t)65536 * 2);
    float* w2p = (float*)alloc((size_t)512 * 4);
    float* b2p2 = (float*)alloc((size_t)2 * 4);
    u16* Wg0 = (u16*)alloc((size_t)24576 * 2);
    u16* Wf1 = (u16*)alloc((size_t)12288 * 2);
    u16* Wf2 = (u16*)alloc((size_t)12288 * 2);
    u16* Wf3 = (u16*)alloc((size_t)12288 * 2);
    float* wpad = (float*)alloc((size_t)OTOT * 4);
    int* flag = (int*)alloc(256);

    u16* V1 = Tx2;                   // compact N x 64
    u16* V2 = Tx2 + (size_t)NN * 64; // compact N x 64

    // zero dc + cursor (contiguous allocations)
    hipMemsetAsync(dc, 0, (size_t)((char*)dis - (char*)dc), stream);

    PtrTab tab;
    for (int i = 0; i < 20; i++) tab.p[i] = d_in[3 + i];

    k_detect<<<1, 256, 0, stream>>>((const u16*)features, flag);
    k_wconv<<<20, 256, 0, stream>>>(tab, flag, wpad);
    k_fold<<<33, 128, 0, stream>>>(wpad, W2s, b2p);
    k_foldc<<<65, 256, 0, stream>>>(wpad, W1c, w2p, b2p2);
    k_foldw0<<<24, 256, 0, stream>>>(wpad, Wg0);
    k_foldw<<<36, 256, 0, stream>>>(wpad, Wf1, Wf2, Wf3);
    k_x0<<<3125, 256, 0, stream>>>(features, flag, X0);
    // 1024 blocks = 4/CU (retry with halved atomics; see k_pae header)
    k_pae<<<1024, 256, 0, stream>>>(zin, wpad, W2s, b2p, ei, flag, ewf, d_out, dc);
    k_scan<<<1, 1024, 0, stream>>>(dc, offs, dis);
    k_csr<<<EE / 256, 256, 0, stream>>>(ei, ewf, dis, offs, cursor, csr_meta);

    // layer 0 (commuted: project-then-propagate, compact V split)
    k_gemm0<<<1563, 256, 0, stream>>>(X0, Wg0, Tx1 /*U*/, Dbuf);
    k_prop0a<<<12500, 256, 0, stream>>>(Tx1, csr_meta, offs, V1, V2);
    k_prop0b<<<12500, 256, 0, stream>>>(V1, V2, csr_meta, offs, Dbuf, h0, flag, d_out);
    // layer 1 (F=64)
    k_prop64<<<12500, 256, 0, stream>>>(h0, csr_meta, offs, Tx1, nullptr, 1.f, 0.f);
    k_prop64<<<12500, 256, 0, stream>>>(Tx1, csr_meta, offs, Tx2, h0, 2.f, -1.f);
    k_gemm<64><<<1563, 256, 0, stream>>>(h0, Tx1, Tx2, Wf1, h1, d_out, 64, flag);
    // layer 2
    k_prop64<<<12500, 256, 0, stream>>>(h1, csr_meta, offs, Tx1, nullptr, 1.f, 0.f);
    k_prop64<<<12500, 256, 0, stream>>>(Tx1, csr_meta, offs, Tx2, h1, 2.f, -1.f);
    k_gemm<64><<<1563, 256, 0, stream>>>(h1, Tx1, Tx2, Wf2, h2, d_out, 128, flag);
    // layer 3
    k_prop64<<<12500, 256, 0, stream>>>(h2, csr_meta, offs, Tx1, nullptr, 1.f, 0.f);
    k_prop64<<<12500, 256, 0, stream>>>(Tx1, csr_meta, offs, Tx2, h2, 2.f, -1.f);
    k_gemm<64><<<1563, 256, 0, stream>>>(h2, Tx1, Tx2, Wf3, h3, d_out, 192, flag);

    // fused classifier (z never materialized)
    k_cls<<<1563, 256, 0, stream>>>(h0, h1, h2, h3, W1c, wpad, w2p, b2p2, flag, d_out);
    (void)in_sizes; (void)n_in; (void)out_size; (void)ws_size;
}

// Round 9
// 886.579 us; speedup vs baseline: 1.2805x; 1.2805x over previous
//
#include <hip/hip_runtime.h>

#define NN 50000
#define EE 1600000

using u16 = unsigned short;
using u32 = unsigned int;
using u64 = unsigned long long;

typedef float f32x4 __attribute__((ext_vector_type(4)));
typedef float f32x2 __attribute__((ext_vector_type(2)));
typedef __bf16 bf16x8 __attribute__((ext_vector_type(8)));
typedef unsigned short u16x8 __attribute__((ext_vector_type(8)));

struct alignas(8) U16x4 { u16 a, b, c, d; };
struct PtrTab { const void* p[20]; };

// canonical fp32 weight-pad offsets
#define OW1 0
#define OB1 768
#define OG 896
#define OBB 1024
#define ORM 1152
#define ORV 1280
#define OW2 1408
#define OB2 17792
#define OCH0 17920
#define OCH1 42496
#define OCH2 54784
#define OCH3 67072
#define OCW1 79360
#define OCB1 144896
#define OCG 145152
#define OCBB 145408
#define OCRM 145664
#define OCRV 145920
#define OCW2 146176
#define OCB2 146688
#define OTOT 146690

// element offsets within d_out (dtype-independent in elements)
#define LG_OFF ((size_t)NN * 256)
#define EW_OFF ((size_t)NN * 256 + (size_t)NN * 2)

__device__ __forceinline__ float bf2f(u16 u) { return __builtin_bit_cast(float, (u32)u << 16); }
__device__ __forceinline__ float bfl(u32 u) { return __builtin_bit_cast(float, u << 16); }
__device__ __forceinline__ float bfh(u32 u) { return __builtin_bit_cast(float, u & 0xffff0000u); }
__device__ __forceinline__ u16 f2bf(float f) {
    u32 u = __builtin_bit_cast(u32, f);
    return (u16)((u + 0x7fffu + ((u >> 16) & 1u)) >> 16);
}

// Input dtype detector: flag=1 -> bf16 inputs, 0 -> fp32 inputs.
__global__ __launch_bounds__(256) void k_detect(const u16* __restrict__ f, int* __restrict__ flag) {
    __shared__ int bad;
    if (threadIdx.x == 0) bad = 0;
    __syncthreads();
    u16 u = f[threadIdx.x];
    int e = (u >> 7) & 0xFF;
    if (e >= 0x90) atomicAdd(&bad, 1);
    __syncthreads();
    if (threadIdx.x == 0) flag[0] = (bad < 16) ? 1 : 0;
}

// Convert all 20 weight arrays into canonical fp32 pad.
__global__ __launch_bounds__(256) void k_wconv(PtrTab tab, const int* __restrict__ flag,
                                               float* __restrict__ wpad) {
    const int SZ[20] = {768, 128, 128, 128, 128, 128, 16384, 128, 24576, 12288, 12288, 12288,
                        65536, 256, 256, 256, 256, 256, 512, 2};
    const int OF[20] = {OW1, OB1, OG, OBB, ORM, ORV, OW2, OB2, OCH0, OCH1, OCH2, OCH3,
                        OCW1, OCB1, OCG, OCBB, OCRM, OCRV, OCW2, OCB2};
    int a = blockIdx.x;
    int n = SZ[a];
    float* dst = wpad + OF[a];
    if (flag[0] != 0) {
        const u16* s = (const u16*)tab.p[a];
        for (int i = threadIdx.x; i < n; i += 256) dst[i] = bf2f(s[i]);
    } else {
        const float* s = (const float*)tab.p[a];
        for (int i = threadIdx.x; i < n; i += 256) dst[i] = s[i];
    }
}

// Fold PAE BN into W2 (MFMA B-frag swizzled bf16) + b2'. k-row permutation
// matches stage-1 MFMA output order in k_pae (kappa(kc,q,j), R6).
__global__ __launch_bounds__(128) void k_fold(const float* __restrict__ wpad,
                                              u16* __restrict__ W2s, float* __restrict__ b2p) {
    const float* g = wpad + OG;
    const float* b = wpad + OBB;
    const float* rm = wpad + ORM;
    const float* rv = wpad + ORV;
    const float* w2 = wpad + OW2;
    const float* b2 = wpad + OB2;
    int blk = blockIdx.x, tid = threadIdx.x;
    if (blk < 32) {
        int kc = blk >> 3, jt = blk & 7;
        int lane = tid & 63, jh = tid >> 6;
        int q = lane >> 4;
        for (int jj = 0; jj < 4; jj++) {
            int j = jh * 4 + jj;
            int k = kc * 32 + ((j < 4) ? (q * 4 + j) : (16 + q * 4 + (j - 4)));
            int jcol = jt * 16 + (lane & 15);
            float s = g[k] * rsqrtf(rv[k] + 1e-5f);
            W2s[((kc * 8 + jt) * 64 + lane) * 8 + j] = f2bf(s * w2[k * 128 + jcol]);
        }
    } else {
        if (tid < 128) {
            int j = tid;
            float acc = b2[j];
            for (int k = 0; k < 128; k++) {
                float s = g[k] * rsqrtf(rv[k] + 1e-5f);
                float t = b[k] - rm[k] * s;
                acc += t * w2[k * 128 + j];
            }
            b2p[j] = acc;
        }
    }
}

// Fold classifier weights: W1c = cls_w1 as MFMA B-fragments (bf16, phase-sliced),
// w2p[j][c] = s_j * cls_w2[j][c], b2p2[c] = cls_b2[c] + sum_j t_j * cls_w2[j][c].
__global__ __launch_bounds__(256) void k_foldc(const float* __restrict__ wpad,
                                               u16* __restrict__ W1c, float* __restrict__ w2p,
                                               float* __restrict__ b2p2) {
    int tid = threadIdx.x;
    if (blockIdx.x < 64) {
        const float* w1 = wpad + OCW1;
        int base = blockIdx.x * 1024 + tid * 4;
#pragma unroll
        for (int u = 0; u < 4; u++) {
            int gi = base + u;
            int j = gi & 7;
            int lane = (gi >> 3) & 63;
            int ct = (gi >> 9) & 15;
            int kc2 = (gi >> 13) & 1;
            int l = gi >> 14;
            int k = l * 64 + kc2 * 32 + ((lane >> 4) & 3) * 8 + j;
            int col = ct * 16 + (lane & 15);
            W1c[gi] = f2bf(w1[k * 256 + col]);
        }
    } else {
        __shared__ float red[8];
        int j = tid;
        float s = wpad[OCG + j] * rsqrtf(wpad[OCRV + j] + 1e-5f);
        float t = wpad[OCBB + j] - wpad[OCRM + j] * s;
        float w0 = wpad[OCW2 + j * 2], w1v = wpad[OCW2 + j * 2 + 1];
        w2p[j * 2] = s * w0;
        w2p[j * 2 + 1] = s * w1v;
        float c0 = t * w0, c1 = t * w1v;
#pragma unroll
        for (int off = 1; off < 64; off <<= 1) {
            c0 += __shfl_xor(c0, off);
            c1 += __shfl_xor(c1, off);
        }
        int wv = tid >> 6, lane = tid & 63;
        if (lane == 0) { red[wv * 2] = c0; red[wv * 2 + 1] = c1; }
        __syncthreads();
        if (tid == 0) b2p2[0] = wpad[OCB2] + red[0] + red[2] + red[4] + red[6];
        if (tid == 1) b2p2[1] = wpad[OCB2 + 1] + red[1] + red[3] + red[5] + red[7];
    }
}

// Fold layers 1-3 ChebConv weights into MFMA B-fragment order (bf16).
__global__ __launch_bounds__(256) void k_foldw(const float* __restrict__ wpad,
                                               u16* __restrict__ Wf1,
                                               u16* __restrict__ Wf2, u16* __restrict__ Wf3) {
    int b = blockIdx.x, tid = threadIdx.x;
    const float* src;
    u16* dst;
    if (b < 12)      { src = wpad + OCH1; dst = Wf1; }
    else if (b < 24) { src = wpad + OCH2; dst = Wf2; b -= 12; }
    else             { src = wpad + OCH3; dst = Wf3; b -= 24; }
    int base = b * 1024 + tid * 4;
#pragma unroll
    for (int u = 0; u < 4; u++) {
        int gi = base + u;
        int jj = gi & 7;
        int lane = (gi >> 3) & 63;
        int ct = (gi >> 9) & 3;
        int kt = gi >> 11;
        int k = kt * 32 + ((lane >> 4) & 3) * 8 + jj;
        int col = ct * 16 + (lane & 15);
        dst[gi] = f2bf(src[k * 64 + col]);
    }
}

// Fold layer-0 weights (commuted form): Wg0 = B-fragments of [W1 | W2 | W0-W2].
__global__ __launch_bounds__(256) void k_foldw0(const float* __restrict__ wpad,
                                                u16* __restrict__ Wg0) {
    const float* src = wpad + OCH0;  // [3][128][64]
    int tid = threadIdx.x;
    int base = blockIdx.x * 1024 + tid * 4;
#pragma unroll
    for (int u = 0; u < 4; u++) {
        int gi = base + u;
        int jj = gi & 7;
        int lane = (gi >> 3) & 63;
        int rest = gi >> 9;      // kt*12 + ct
        int ct = rest % 12;
        int kt = rest / 12;
        int k = kt * 32 + ((lane >> 4) & 3) * 8 + jj;
        int cl = (lane & 15);
        float v;
        if (ct < 4) {
            v = src[(1 * 128 + k) * 64 + ct * 16 + cl];                    // W1
        } else if (ct < 8) {
            v = src[(2 * 128 + k) * 64 + (ct - 4) * 16 + cl];              // W2
        } else {
            int c = (ct - 8) * 16 + cl;
            v = src[(0 * 128 + k) * 64 + c] - src[(2 * 128 + k) * 64 + c]; // W0-W2
        }
        Wg0[gi] = f2bf(v);
    }
}

// features (either dtype) -> bf16 X0.
__global__ __launch_bounds__(256) void k_x0(const void* __restrict__ feat, const int* __restrict__ flag,
                                            u16* __restrict__ X0) {
    int i = blockIdx.x * 256 + threadIdx.x;
    if (flag[0] != 0) {
        ((uint4*)X0)[i] = ((const uint4*)feat)[i];
    } else {
        const float4* f = (const float4*)feat;
        float4 a = f[2 * i], b = f[2 * i + 1];
        u16x8 o;
        o[0] = f2bf(a.x); o[1] = f2bf(a.y); o[2] = f2bf(a.z); o[3] = f2bf(a.w);
        o[4] = f2bf(b.x); o[5] = f2bf(b.y); o[6] = f2bf(b.z); o[7] = f2bf(b.w);
        ((uint4*)X0)[i] = __builtin_bit_cast(uint4, o);
    }
}

// PAE, v9: both layers MFMA + packed-f32x2 epilogue (R6/R7).
// R8 POST-MORTEM: __launch_bounds__(256,4) forced VGPR 80->64 -> massive
// scratch spill (FETCH+WRITE 1.67GB, 489us). The right knob for 4 blocks/CU
// is GRID SIZE: keep (256,3) bounds (VGPR stays 80, 6 waves/SIMD allowed;
// LDS 4x33.3KB = 133KB fits) and launch 1024 blocks. No spill, 4 resident.
__global__ __launch_bounds__(256, 3) void k_pae(const void* __restrict__ zin, const float* __restrict__ wpad,
                                                const u16* __restrict__ W2sg, const float* __restrict__ b2p,
                                                const int* __restrict__ ei, const int* __restrict__ flag,
                                                float* __restrict__ ewf, void* __restrict__ dout,
                                                u64* __restrict__ dc) {
    __shared__ __align__(16) u16 sW2[16384];
    __shared__ float sB2[128];
    int tid = threadIdx.x;
    for (int i = tid; i < 8192; i += 256) ((u32*)sW2)[i] = ((const u32*)W2sg)[i];
    if (tid < 128) sB2[tid] = b2p[tid];
    __syncthreads();

    bool isbf = flag[0] != 0;
    int wv = __builtin_amdgcn_readfirstlane(tid >> 6);
    int lane = tid & 63;
    int quad = lane >> 4, lrow = lane & 15, jc = lane & 15;
    u32 qm = (quad == 0) ? 0xffffffffu : 0u;  // B-frag mask: only quad 0 supplies z

    // loop-invariant stage-1 operands: W1 A-frags (8 tiles) + b1 C-inits
    uint4 w1f[8];
    f32x4 cb[8];
#pragma unroll
    for (int kt = 0; kt < 8; kt++) {
        u32 a = 0, b = 0, c = 0;
        if (quad == 0) {
            int col = kt * 16 + lrow;
            a = (u32)f2bf(wpad[OW1 + 0 * 128 + col]) | ((u32)f2bf(wpad[OW1 + 1 * 128 + col]) << 16);
            b = (u32)f2bf(wpad[OW1 + 2 * 128 + col]) | ((u32)f2bf(wpad[OW1 + 3 * 128 + col]) << 16);
            c = (u32)f2bf(wpad[OW1 + 4 * 128 + col]) | ((u32)f2bf(wpad[OW1 + 5 * 128 + col]) << 16);
        }
        w1f[kt] = (uint4){a, b, c, 0u};
#pragma unroll
        for (int r = 0; r < 4; r++) cb[kt][r] = wpad[OB1 + kt * 16 + quad * 4 + r];
    }

    int gw = blockIdx.x * 4 + wv;
    const int ngroups = EE / 16;
    const int gstep = gridDim.x * 4;

    uint2 pb0, pb1, pb2;       // bf16 Z prefetch (24B row)
    float4 pf0, pf1, pf2;      // fp32 Z prefetch (48B row)
    if (gw < ngroups) {
        if (isbf) {
            const uint2* zp = (const uint2*)((const u16*)zin + (size_t)(gw * 16 + lrow) * 12);
            pb0 = zp[0]; pb1 = zp[1]; pb2 = zp[2];
        } else {
            const float4* zp = (const float4*)((const float*)zin + (size_t)(gw * 16 + lrow) * 12);
            pf0 = zp[0]; pf1 = zp[1]; pf2 = zp[2];
        }
    }

#pragma unroll 1
    for (int gidx = gw; gidx < ngroups; gidx += gstep) {
        int e0 = gidx * 16;
        float z1[6], z2[6];
        if (isbf) {
            z1[0] = bfl(pb0.x); z1[1] = bfh(pb0.x); z1[2] = bfl(pb0.y); z1[3] = bfh(pb0.y);
            z1[4] = bfl(pb1.x); z1[5] = bfh(pb1.x);
            z2[0] = bfl(pb1.y); z2[1] = bfh(pb1.y); z2[2] = bfl(pb2.x); z2[3] = bfh(pb2.x);
            z2[4] = bfl(pb2.y); z2[5] = bfh(pb2.y);
        } else {
            z1[0] = pf0.x; z1[1] = pf0.y; z1[2] = pf0.z; z1[3] = pf0.w; z1[4] = pf1.x; z1[5] = pf1.y;
            z2[0] = pf1.z; z2[1] = pf1.w; z2[2] = pf2.x; z2[3] = pf2.y; z2[4] = pf2.z; z2[5] = pf2.w;
        }
        // issue next group's Z loads now -- they complete under this group's compute
        int gn = gidx + gstep;
        if (gn < ngroups) {
            if (isbf) {
                const uint2* zp = (const uint2*)((const u16*)zin + (size_t)(gn * 16 + lrow) * 12);
                pb0 = zp[0]; pb1 = zp[1]; pb2 = zp[2];
            } else {
                const float4* zp = (const float4*)((const float*)zin + (size_t)(gn * 16 + lrow) * 12);
                pf0 = zp[0]; pf1 = zp[1]; pf2 = zp[2];
            }
        }
        // hoist epilogue row indices
        int rows[4];
        if (jc == 0) {
#pragma unroll
            for (int r = 0; r < 4; r++) rows[r] = ei[e0 + quad * 4 + r];
        }

        // build z B-frags (quad 0 only; lossless round-trip for bf16 inputs)
        u32 za0, za1, za2, zb0, zb1, zb2;
        asm("v_cvt_pk_bf16_f32 %0, %1, %2" : "=v"(za0) : "v"(z1[0]), "v"(z1[1]));
        asm("v_cvt_pk_bf16_f32 %0, %1, %2" : "=v"(za1) : "v"(z1[2]), "v"(z1[3]));
        asm("v_cvt_pk_bf16_f32 %0, %1, %2" : "=v"(za2) : "v"(z1[4]), "v"(z1[5]));
        asm("v_cvt_pk_bf16_f32 %0, %1, %2" : "=v"(zb0) : "v"(z2[0]), "v"(z2[1]));
        asm("v_cvt_pk_bf16_f32 %0, %1, %2" : "=v"(zb1) : "v"(z2[2]), "v"(z2[3]));
        asm("v_cvt_pk_bf16_f32 %0, %1, %2" : "=v"(zb2) : "v"(z2[4]), "v"(z2[5]));
        uint4 zu1 = {za0 & qm, za1 & qm, za2 & qm, 0u};
        uint4 zu2 = {zb0 & qm, zb1 & qm, zb2 & qm, 0u};
        bf16x8 zf1 = __builtin_bit_cast(bf16x8, zu1);
        bf16x8 zf2 = __builtin_bit_cast(bf16x8, zu2);

        // stage 1 + pack, encoding 1
        bf16x8 a1f[4], a2f[4];
        {
            f32x4 c1[8];
#pragma unroll
            for (int kt = 0; kt < 8; kt++)
                c1[kt] = __builtin_amdgcn_mfma_f32_16x16x32_bf16(
                    __builtin_bit_cast(bf16x8, w1f[kt]), zf1, cb[kt], 0, 0, 0);
#pragma unroll
            for (int kc = 0; kc < 4; kc++) {
                float h0 = fmaxf(c1[2 * kc][0], 0.f), h1 = fmaxf(c1[2 * kc][1], 0.f);
                float h2 = fmaxf(c1[2 * kc][2], 0.f), h3 = fmaxf(c1[2 * kc][3], 0.f);
                float h4 = fmaxf(c1[2 * kc + 1][0], 0.f), h5 = fmaxf(c1[2 * kc + 1][1], 0.f);
                float h6 = fmaxf(c1[2 * kc + 1][2], 0.f), h7 = fmaxf(c1[2 * kc + 1][3], 0.f);
                u32 p0, p1, p2, p3;
                asm("v_cvt_pk_bf16_f32 %0, %1, %2" : "=v"(p0) : "v"(h0), "v"(h1));
                asm("v_cvt_pk_bf16_f32 %0, %1, %2" : "=v"(p1) : "v"(h2), "v"(h3));
                asm("v_cvt_pk_bf16_f32 %0, %1, %2" : "=v"(p2) : "v"(h4), "v"(h5));
                asm("v_cvt_pk_bf16_f32 %0, %1, %2" : "=v"(p3) : "v"(h6), "v"(h7));
                uint4 au = {p0, p1, p2, p3};
                a1f[kc] = __builtin_bit_cast(bf16x8, au);
            }
        }
        // stage 1 + pack, encoding 2
        {
            f32x4 c2[8];
#pragma unroll
            for (int kt = 0; kt < 8; kt++)
                c2[kt] = __builtin_amdgcn_mfma_f32_16x16x32_bf16(
                    __builtin_bit_cast(bf16x8, w1f[kt]), zf2, cb[kt], 0, 0, 0);
#pragma unroll
            for (int kc = 0; kc < 4; kc++) {
                float h0 = fmaxf(c2[2 * kc][0], 0.f), h1 = fmaxf(c2[2 * kc][1], 0.f);
                float h2 = fmaxf(c2[2 * kc][2], 0.f), h3 = fmaxf(c2[2 * kc][3], 0.f);
                float h4 = fmaxf(c2[2 * kc + 1][0], 0.f), h5 = fmaxf(c2[2 * kc + 1][1], 0.f);
                float h6 = fmaxf(c2[2 * kc + 1][2], 0.f), h7 = fmaxf(c2[2 * kc + 1][3], 0.f);
                u32 p0, p1, p2, p3;
                asm("v_cvt_pk_bf16_f32 %0, %1, %2" : "=v"(p0) : "v"(h0), "v"(h1));
                asm("v_cvt_pk_bf16_f32 %0, %1, %2" : "=v"(p1) : "v"(h2), "v"(h3));
                asm("v_cvt_pk_bf16_f32 %0, %1, %2" : "=v"(p2) : "v"(h4), "v"(h5));
                asm("v_cvt_pk_bf16_f32 %0, %1, %2" : "=v"(p3) : "v"(h6), "v"(h7));
                uint4 au = {p0, p1, p2, p3};
                a2f[kc] = __builtin_bit_cast(bf16x8, au);
            }
        }

        // packed cosine accumulators: 6 independent f32x2 chains
        f32x2 numA = {0.f, 0.f}, numB = {0.f, 0.f};
        f32x2 q1A = {0.f, 0.f}, q1B = {0.f, 0.f};
        f32x2 q2A = {0.f, 0.f}, q2B = {0.f, 0.f};
        // jt NOT unrolled: keeps ds_read hoisting bounded (spill guard).
#pragma unroll 1
        for (int jt = 0; jt < 8; jt++) {
            f32x4 acc1 = {0.f, 0.f, 0.f, 0.f}, acc2 = {0.f, 0.f, 0.f, 0.f};
#pragma unroll
            for (int kc = 0; kc < 4; kc++) {
                bf16x8 bb = *reinterpret_cast<const bf16x8*>(&sW2[((kc * 8 + jt) * 64 + lane) * 8]);
                acc1 = __builtin_amdgcn_mfma_f32_16x16x32_bf16(a1f[kc], bb, acc1, 0, 0, 0);
                acc2 = __builtin_amdgcn_mfma_f32_16x16x32_bf16(a2f[kc], bb, acc2, 0, 0, 0);
            }
            float bbias = sB2[jt * 16 + jc];
            f32x2 bb2 = {bbias, bbias};
            f32x2 a1lo = {acc1[0], acc1[1]}, a1hi = {acc1[2], acc1[3]};
            f32x2 a2lo = {acc2[0], acc2[1]}, a2hi = {acc2[2], acc2[3]};
            f32x2 h1A, h1B, h2A, h2B;
            asm("v_pk_add_f32 %0, %1, %2" : "=v"(h1A) : "v"(a1lo), "v"(bb2));
            asm("v_pk_add_f32 %0, %1, %2" : "=v"(h1B) : "v"(a1hi), "v"(bb2));
            asm("v_pk_add_f32 %0, %1, %2" : "=v"(h2A) : "v"(a2lo), "v"(bb2));
            asm("v_pk_add_f32 %0, %1, %2" : "=v"(h2B) : "v"(a2hi), "v"(bb2));
            asm("v_pk_fma_f32 %0, %1, %2, %0" : "+v"(numA) : "v"(h1A), "v"(h2A));
            asm("v_pk_fma_f32 %0, %1, %2, %0" : "+v"(numB) : "v"(h1B), "v"(h2B));
            asm("v_pk_fma_f32 %0, %1, %2, %0" : "+v"(q1A) : "v"(h1A), "v"(h1A));
            asm("v_pk_fma_f32 %0, %1, %2, %0" : "+v"(q1B) : "v"(h1B), "v"(h1B));
            asm("v_pk_fma_f32 %0, %1, %2, %0" : "+v"(q2A) : "v"(h2A), "v"(h2A));
            asm("v_pk_fma_f32 %0, %1, %2, %0" : "+v"(q2B) : "v"(h2B), "v"(h2B));
        }
        float num[4] = {numA[0], numA[1], numB[0], numB[1]};
        float q1[4] = {q1A[0], q1A[1], q1B[0], q1B[1]};
        float q2[4] = {q2A[0], q2A[1], q2B[0], q2B[1]};
#pragma unroll
        for (int off = 1; off < 16; off <<= 1) {
#pragma unroll
            for (int r = 0; r < 4; r++) {
                num[r] += __shfl_xor(num[r], off);
                q1[r] += __shfl_xor(q1[r], off);
                q2[r] += __shfl_xor(q2[r], off);
            }
        }
        if (jc == 0) {
#pragma unroll
            for (int r = 0; r < 4; r++) {
                int e = e0 + quad * 4 + r;
                float den = fmaxf(sqrtf(q1[r]) * sqrtf(q2[r]), 1e-8f);
                float wgt = (num[r] / den + 1.f) * 0.5f;
                if (!(wgt == wgt)) wgt = 0.5f;  // NaN guard: makes failures localizable
                ewf[e] = wgt;
                if (isbf) ((u16*)dout)[EW_OFF + e] = f2bf(wgt);
                else ((float*)dout)[EW_OFF + e] = wgt;
                // one u64 atomic: hi32 = count(+1), lo32 = wgt in 8.23 fixed point
                u32 fx = (u32)(wgt * 8388608.f + 0.5f);
                atomicAdd(dc + rows[r], (((u64)1) << 32) | (u64)fx);
            }
        }
    }
}

// Exclusive scan of cnt (hi32 of dc) -> offs; fused dis = rsqrt(deg).
__global__ __launch_bounds__(1024) void k_scan(const u64* __restrict__ dc,
                                               int* __restrict__ offs, float* __restrict__ dis) {
    __shared__ int wsum[16];
    __shared__ int carry;
    int tid = threadIdx.x;
    int wv = tid >> 6, lane = tid & 63;
    if (tid == 0) carry = 0;
    __syncthreads();
    for (int c = 0; c < 49; c++) {
        int i = c * 1024 + tid;
        u64 v64 = (i < NN) ? dc[i] : 0ull;
        int v = (int)(v64 >> 32);
        if (i < NN) {
            float d = (float)(u32)v64 * (1.f / 8388608.f);
            dis[i] = d > 0.f ? rsqrtf(d) : 0.f;
        }
        int x = v;
#pragma unroll
        for (int off = 1; off < 64; off <<= 1) {
            int t = __shfl_up(x, off);
            if (lane >= off) x += t;
        }
        if (lane == 63) wsum[wv] = x;
        __syncthreads();
        if (tid < 16) {
            int s = wsum[tid];
#pragma unroll
            for (int off = 1; off < 16; off <<= 1) {
                int t = __shfl_up(s, off, 16);
                if (tid >= off) s += t;
            }
            wsum[tid] = s;
        }
        __syncthreads();
        int base = carry + (wv > 0 ? wsum[wv - 1] : 0);
        if (i < NN) offs[i] = base + x - v;
        __syncthreads();
        if (tid == 0) carry += wsum[15];
        __syncthreads();
    }
    if (tid == 0) offs[NN] = carry;
}

// CSR scatter: fused (col, norm) uint2 metadata — one 8B load per edge in prop.
__global__ __launch_bounds__(256) void k_csr(const int* __restrict__ ei, const float* __restrict__ ewf,
                                             const float* __restrict__ dis, const int* __restrict__ offs,
                                             int* __restrict__ cursor, uint2* __restrict__ csr_meta) {
    int e = blockIdx.x * 256 + threadIdx.x;
    int r = ei[e], c = ei[EE + e];
    float wgt = ewf[e];
    int pos = offs[r] + atomicAdd(cursor + r, 1);
    float nrm = -dis[r] * wgt * dis[c];
    csr_meta[pos] = make_uint2((u32)c, __builtin_bit_cast(u32, nrm));
}

// ---- propagation kernels (R7: masked full-width tails, no serial loops) ----

// Layer-0 first prop: 128-wide gather of U, output SPLIT into compact V1/V2.
__global__ __launch_bounds__(256) void k_prop0a(const u16* __restrict__ U, const uint2* __restrict__ csr_meta,
                                                const int* __restrict__ offs,
                                                u16* __restrict__ V1, u16* __restrict__ V2) {
    int lane = threadIdx.x & 63;
    int wv = threadIdx.x >> 6;
    int node = blockIdx.x * 4 + wv;
    int s = offs[node], e = offs[node + 1];
    int sub = lane >> 4;
    int fl = lane & 15;
    const uint4* sv = (const uint4*)U;  // row = 16 uint4 (128 bf16)
    float a[8] = {0, 0, 0, 0, 0, 0, 0, 0};
    int p = s;
    if (p < e) {
        int i0 = p + sub, i1 = p + 4 + sub;
        uint2 m0 = csr_meta[min(i0, e - 1)];
        uint2 m1 = csr_meta[min(i1, e - 1)];
        float w0 = (i0 < e) ? __builtin_bit_cast(float, m0.y) : 0.f;
        float w1 = (i1 < e) ? __builtin_bit_cast(float, m1.y) : 0.f;
        while (true) {
            uint4 v0 = sv[(size_t)m0.x * 16 + fl];
            uint4 v1 = sv[(size_t)m1.x * 16 + fl];
            float w0c = w0, w1c = w1;
            p += 8;
            bool more = p < e;
            if (more) {
                i0 = p + sub; i1 = p + 4 + sub;
                m0 = csr_meta[min(i0, e - 1)];
                m1 = csr_meta[min(i1, e - 1)];
                w0 = (i0 < e) ? __builtin_bit_cast(float, m0.y) : 0.f;
                w1 = (i1 < e) ? __builtin_bit_cast(float, m1.y) : 0.f;
            }
            a[0] = fmaf(w0c, bfl(v0.x), a[0]); a[1] = fmaf(w0c, bfh(v0.x), a[1]);
            a[2] = fmaf(w0c, bfl(v0.y), a[2]); a[3] = fmaf(w0c, bfh(v0.y), a[3]);
            a[4] = fmaf(w0c, bfl(v0.z), a[4]); a[5] = fmaf(w0c, bfh(v0.z), a[5]);
            a[6] = fmaf(w0c, bfl(v0.w), a[6]); a[7] = fmaf(w0c, bfh(v0.w), a[7]);
            a[0] = fmaf(w1c, bfl(v1.x), a[0]); a[1] = fmaf(w1c, bfh(v1.x), a[1]);
            a[2] = fmaf(w1c, bfl(v1.y), a[2]); a[3] = fmaf(w1c, bfh(v1.y), a[3]);
            a[4] = fmaf(w1c, bfl(v1.z), a[4]); a[5] = fmaf(w1c, bfh(v1.z), a[5]);
            a[6] = fmaf(w1c, bfl(v1.w), a[6]); a[7] = fmaf(w1c, bfh(v1.w), a[7]);
            if (!more) break;
        }
    }
#pragma unroll
    for (int i = 0; i < 8; i++) {
        a[i] += __shfl_xor(a[i], 16);
        a[i] += __shfl_xor(a[i], 32);
    }
    if (sub == 0) {
        uint4 ov;
        ov.x = (u32)f2bf(a[0]) | ((u32)f2bf(a[1]) << 16);
        ov.y = (u32)f2bf(a[2]) | ((u32)f2bf(a[3]) << 16);
        ov.z = (u32)f2bf(a[4]) | ((u32)f2bf(a[5]) << 16);
        ov.w = (u32)f2bf(a[6]) | ((u32)f2bf(a[7]) << 16);
        if (fl < 8) ((uint4*)V1)[(size_t)node * 8 + fl] = ov;
        else ((uint4*)V2)[(size_t)node * 8 + (fl - 8)] = ov;
    }
}

// Layer-0 second prop: gathers COMPACT V2 (N x 64), fuses combine
// h0 = relu(D + V1 + 2*S); writes h0 (bf16) and jk slice 0.
__global__ __launch_bounds__(256) void k_prop0b(const u16* __restrict__ V1, const u16* __restrict__ V2,
                                                const uint2* __restrict__ csr_meta,
                                                const int* __restrict__ offs, const u16* __restrict__ D,
                                                u16* __restrict__ h0out, const int* __restrict__ flag,
                                                void* __restrict__ jkout) {
    int lane = threadIdx.x & 63;
    int wv = threadIdx.x >> 6;
    int node = blockIdx.x * 4 + wv;
    int s = offs[node], e = offs[node + 1];
    int sub = lane >> 3;
    int fl = lane & 7;
    const uint4* sv = (const uint4*)V2;  // row = 8 uint4 (64 bf16)
    float a[8] = {0, 0, 0, 0, 0, 0, 0, 0};
    int p = s;
    if (p < e) {
        int i0 = p + sub, i1 = p + 8 + sub;
        uint2 m0 = csr_meta[min(i0, e - 1)];
        uint2 m1 = csr_meta[min(i1, e - 1)];
        float w0 = (i0 < e) ? __builtin_bit_cast(float, m0.y) : 0.f;
        float w1 = (i1 < e) ? __builtin_bit_cast(float, m1.y) : 0.f;
        while (true) {
            uint4 v0 = sv[(size_t)m0.x * 8 + fl];
            uint4 v1 = sv[(size_t)m1.x * 8 + fl];
            float w0c = w0, w1c = w1;
            p += 16;
            bool more = p < e;
            if (more) {
                i0 = p + sub; i1 = p + 8 + sub;
                m0 = csr_meta[min(i0, e - 1)];
                m1 = csr_meta[min(i1, e - 1)];
                w0 = (i0 < e) ? __builtin_bit_cast(float, m0.y) : 0.f;
                w1 = (i1 < e) ? __builtin_bit_cast(float, m1.y) : 0.f;
            }
            a[0] = fmaf(w0c, bfl(v0.x), a[0]); a[1] = fmaf(w0c, bfh(v0.x), a[1]);
            a[2] = fmaf(w0c, bfl(v0.y), a[2]); a[3] = fmaf(w0c, bfh(v0.y), a[3]);
            a[4] = fmaf(w0c, bfl(v0.z), a[4]); a[5] = fmaf(w0c, bfh(v0.z), a[5]);
            a[6] = fmaf(w0c, bfl(v0.w), a[6]); a[7] = fmaf(w0c, bfh(v0.w), a[7]);
            a[0] = fmaf(w1c, bfl(v1.x), a[0]); a[1] = fmaf(w1c, bfh(v1.x), a[1]);
            a[2] = fmaf(w1c, bfl(v1.y), a[2]); a[3] = fmaf(w1c, bfh(v1.y), a[3]);
            a[4] = fmaf(w1c, bfl(v1.z), a[4]); a[5] = fmaf(w1c, bfh(v1.z), a[5]);
            a[6] = fmaf(w1c, bfl(v1.w), a[6]); a[7] = fmaf(w1c, bfh(v1.w), a[7]);
            if (!more) break;
        }
    }
#pragma unroll
    for (int i = 0; i < 8; i++) {
        a[i] += __shfl_xor(a[i], 8);
        a[i] += __shfl_xor(a[i], 16);
        a[i] += __shfl_xor(a[i], 32);
    }
    if (sub == 0) {
        uint4 v1 = ((const uint4*)V1)[(size_t)node * 8 + fl];
        uint4 dv = ((const uint4*)D)[(size_t)node * 8 + fl];
        float o[8];
        o[0] = fmaf(2.f, a[0], bfl(v1.x) + bfl(dv.x)); o[1] = fmaf(2.f, a[1], bfh(v1.x) + bfh(dv.x));
        o[2] = fmaf(2.f, a[2], bfl(v1.y) + bfl(dv.y)); o[3] = fmaf(2.f, a[3], bfh(v1.y) + bfh(dv.y));
        o[4] = fmaf(2.f, a[4], bfl(v1.z) + bfl(dv.z)); o[5] = fmaf(2.f, a[5], bfh(v1.z) + bfh(dv.z));
        o[6] = fmaf(2.f, a[6], bfl(v1.w) + bfl(dv.w)); o[7] = fmaf(2.f, a[7], bfh(v1.w) + bfh(dv.w));
#pragma unroll
        for (int i = 0; i < 8; i++) o[i] = fmaxf(o[i], 0.f);
        uint4 ov;
        ov.x = (u32)f2bf(o[0]) | ((u32)f2bf(o[1]) << 16);
        ov.y = (u32)f2bf(o[2]) | ((u32)f2bf(o[3]) << 16);
        ov.z = (u32)f2bf(o[4]) | ((u32)f2bf(o[5]) << 16);
        ov.w = (u32)f2bf(o[6]) | ((u32)f2bf(o[7]) << 16);
        ((uint4*)h0out)[(size_t)node * 8 + fl] = ov;
        if (flag[0] != 0) {
            ((uint4*)jkout)[(size_t)node * 32 + fl] = ov;  // jk row = 32 uint4, slice 0
        } else {
            float* jf = (float*)jkout + (size_t)node * 256 + fl * 8;
#pragma unroll
            for (int i = 0; i < 8; i++) jf[i] = o[i];
        }
    }
}

// Layers 1-3 propagation: 64-wide gather, masked tail, alpha/beta epilogue.
__global__ __launch_bounds__(256) void k_prop64(const u16* __restrict__ src, const uint2* __restrict__ csr_meta,
                                                const int* __restrict__ offs,
                                                u16* __restrict__ out, const u16* __restrict__ base,
                                                float alpha, float beta) {
    int lane = threadIdx.x & 63;
    int wv = threadIdx.x >> 6;
    int node = blockIdx.x * 4 + wv;
    int s = offs[node], e = offs[node + 1];
    int sub = lane >> 3;
    int fl = lane & 7;
    const uint4* sv = (const uint4*)src;  // row = 8 uint4 (64 bf16)
    float a[8] = {0, 0, 0, 0, 0, 0, 0, 0};
    int p = s;
    if (p < e) {
        int i0 = p + sub, i1 = p + 8 + sub;
        uint2 m0 = csr_meta[min(i0, e - 1)];
        uint2 m1 = csr_meta[min(i1, e - 1)];
        float w0 = (i0 < e) ? __builtin_bit_cast(float, m0.y) : 0.f;
        float w1 = (i1 < e) ? __builtin_bit_cast(float, m1.y) : 0.f;
        while (true) {
            uint4 v0 = sv[(size_t)m0.x * 8 + fl];
            uint4 v1 = sv[(size_t)m1.x * 8 + fl];
            float w0c = w0, w1c = w1;
            p += 16;
            bool more = p < e;
            if (more) {
                i0 = p + sub; i1 = p + 8 + sub;
                m0 = csr_meta[min(i0, e - 1)];
                m1 = csr_meta[min(i1, e - 1)];
                w0 = (i0 < e) ? __builtin_bit_cast(float, m0.y) : 0.f;
                w1 = (i1 < e) ? __builtin_bit_cast(float, m1.y) : 0.f;
            }
            a[0] = fmaf(w0c, bfl(v0.x), a[0]); a[1] = fmaf(w0c, bfh(v0.x), a[1]);
            a[2] = fmaf(w0c, bfl(v0.y), a[2]); a[3] = fmaf(w0c, bfh(v0.y), a[3]);
            a[4] = fmaf(w0c, bfl(v0.z), a[4]); a[5] = fmaf(w0c, bfh(v0.z), a[5]);
            a[6] = fmaf(w0c, bfl(v0.w), a[6]); a[7] = fmaf(w0c, bfh(v0.w), a[7]);
            a[0] = fmaf(w1c, bfl(v1.x), a[0]); a[1] = fmaf(w1c, bfh(v1.x), a[1]);
            a[2] = fmaf(w1c, bfl(v1.y), a[2]); a[3] = fmaf(w1c, bfh(v1.y), a[3]);
            a[4] = fmaf(w1c, bfl(v1.z), a[4]); a[5] = fmaf(w1c, bfh(v1.z), a[5]);
            a[6] = fmaf(w1c, bfl(v1.w), a[6]); a[7] = fmaf(w1c, bfh(v1.w), a[7]);
            if (!more) break;
        }
    }
#pragma unroll
    for (int i = 0; i < 8; i++) {
        a[i] += __shfl_xor(a[i], 8);
        a[i] += __shfl_xor(a[i], 16);
        a[i] += __shfl_xor(a[i], 32);
    }
    if (sub == 0) {
        float o[8];
#pragma unroll
        for (int i = 0; i < 8; i++) o[i] = alpha * a[i];
        if (beta != 0.f) {
            uint4 bv = ((const uint4*)base)[(size_t)node * 8 + fl];
            o[0] = fmaf(beta, bfl(bv.x), o[0]); o[1] = fmaf(beta, bfh(bv.x), o[1]);
            o[2] = fmaf(beta, bfl(bv.y), o[2]); o[3] = fmaf(beta, bfh(bv.y), o[3]);
            o[4] = fmaf(beta, bfl(bv.z), o[4]); o[5] = fmaf(beta, bfh(bv.z), o[5]);
            o[6] = fmaf(beta, bfl(bv.w), o[6]); o[7] = fmaf(beta, bfh(bv.w), o[7]);
        }
        uint4 ov;
        ov.x = (u32)f2bf(o[0]) | ((u32)f2bf(o[1]) << 16);
        ov.y = (u32)f2bf(o[2]) | ((u32)f2bf(o[3]) << 16);
        ov.z = (u32)f2bf(o[4]) | ((u32)f2bf(o[5]) << 16);
        ov.w = (u32)f2bf(o[6]) | ((u32)f2bf(o[7]) << 16);
        ((uint4*)out)[(size_t)node * 8 + fl] = ov;
    }
}

// Layer-0 projection gemm (commuted form): G = X @ [W1 | W2 | W0-W2],
// cols 0..127 -> U (N x 128), cols 128..191 -> D (N x 64). No relu.
__global__ __launch_bounds__(256) void k_gemm0(const u16* __restrict__ X0, const u16* __restrict__ Wg0,
                                               u16* __restrict__ U, u16* __restrict__ D) {
    __shared__ __align__(16) u16 sB[4 * 12 * 64 * 8];  // 48KB
    int tid = threadIdx.x;
    for (int i = tid; i < 12288; i += 256) ((u32*)sB)[i] = ((const u32*)Wg0)[i];
    __syncthreads();

    int wv = __builtin_amdgcn_readfirstlane(tid >> 6);
    int lane = tid & 63;
    int quad = lane >> 4, jc = lane & 15;
    int pair = wv >> 1;   // row group
    int half = wv & 1;    // column half (96 cols each)
    int nb = blockIdx.x * 32 + pair * 16;
    int row = nb + jc;
    if (row > NN - 1) row = NN - 1;

    uint4 av[4];
#pragma unroll
    for (int kt = 0; kt < 4; kt++)
        av[kt] = *(const uint4*)(X0 + (size_t)row * 128 + kt * 32 + quad * 8);

    f32x4 acc[6] = {{0.f, 0.f, 0.f, 0.f}, {0.f, 0.f, 0.f, 0.f}, {0.f, 0.f, 0.f, 0.f},
                    {0.f, 0.f, 0.f, 0.f}, {0.f, 0.f, 0.f, 0.f}, {0.f, 0.f, 0.f, 0.f}};
#pragma unroll
    for (int kt = 0; kt < 4; kt++) {
        bf16x8 af = __builtin_bit_cast(bf16x8, av[kt]);
#pragma unroll
        for (int ct = 0; ct < 6; ct++) {
            int g = half * 6 + ct;
            bf16x8 b0 = *reinterpret_cast<const bf16x8*>(&sB[((kt * 12 + g) * 64 + lane) * 8]);
            acc[ct] = __builtin_amdgcn_mfma_f32_16x16x32_bf16(af, b0, acc[ct], 0, 0, 0);
        }
    }

#pragma unroll
    for (int ct = 0; ct < 6; ct++) {
        int g = half * 6 + ct;
        int j = g * 16 + jc;
#pragma unroll
        for (int r = 0; r < 4; r++) {
            int n = nb + quad * 4 + r;
            if (n < NN) {
                float v = acc[ct][r];
                if (j < 128) U[(size_t)n * 128 + j] = f2bf(v);
                else D[(size_t)n * 64 + (j - 128)] = f2bf(v);
            }
        }
    }
}

// ChebConv mix via MFMA -> bf16 h + jk slice (out dtype). Layers 1-3 (F=64).
template <int F>
__global__ __launch_bounds__(256) void k_gemm(const u16* __restrict__ X0, const u16* __restrict__ X1,
                                              const u16* __restrict__ X2, const u16* __restrict__ Wf,
                                              u16* __restrict__ Hout, void* __restrict__ jk, int jkoff,
                                              const int* __restrict__ flag) {
    constexpr int KT = (3 * F) / 32;  // 6 (F=64)
    __shared__ __align__(16) u16 sB[KT * 4 * 64 * 8];
    int tid = threadIdx.x;
    for (int i = tid; i < KT * 4 * 64 * 4; i += 256) ((u32*)sB)[i] = ((const u32*)Wf)[i];
    __syncthreads();

    bool isbf = flag[0] != 0;
    int wv = __builtin_amdgcn_readfirstlane(tid >> 6);
    int lane = tid & 63;
    int quad = lane >> 4, jc = lane & 15;
    int pair = wv >> 1;   // row group
    int half = wv & 1;    // column half (32 cols)
    int nb = blockIdx.x * 32 + pair * 16;
    int row = nb + jc;
    if (row > NN - 1) row = NN - 1;

    uint4 av[KT];
#pragma unroll
    for (int kt = 0; kt < KT; kt++) {
        int kg = kt * 32 + quad * 8;
        const u16* Xp;
        int kk;
        if (kg < F) { Xp = X0; kk = kg; }
        else if (kg < 2 * F) { Xp = X1; kk = kg - F; }
        else { Xp = X2; kk = kg - 2 * F; }
        av[kt] = *(const uint4*)(Xp + (size_t)row * F + kk);
    }

    f32x4 acc0 = {0.f, 0.f, 0.f, 0.f}, acc1 = {0.f, 0.f, 0.f, 0.f};
#pragma unroll
    for (int kt = 0; kt < KT; kt++) {
        bf16x8 af = __builtin_bit_cast(bf16x8, av[kt]);
        bf16x8 b0 = *reinterpret_cast<const bf16x8*>(&sB[((kt * 4 + half * 2 + 0) * 64 + lane) * 8]);
        bf16x8 b1 = *reinterpret_cast<const bf16x8*>(&sB[((kt * 4 + half * 2 + 1) * 64 + lane) * 8]);
        acc0 = __builtin_amdgcn_mfma_f32_16x16x32_bf16(af, b0, acc0, 0, 0, 0);
        acc1 = __builtin_amdgcn_mfma_f32_16x16x32_bf16(af, b1, acc1, 0, 0, 0);
    }

#pragma unroll
    for (int ct = 0; ct < 2; ct++) {
        f32x4 a = ct ? acc1 : acc0;
        int j = (half * 2 + ct) * 16 + jc;
#pragma unroll
        for (int r = 0; r < 4; r++) {
            int n = nb + quad * 4 + r;
            if (n < NN) {
                float v = fmaxf(a[r], 0.f);
                Hout[(size_t)n * 64 + j] = f2bf(v);
                if (isbf) ((u16*)jk)[(size_t)n * 256 + jkoff + j] = f2bf(v);
                else ((float*)jk)[(size_t)n * 256 + jkoff + j] = v;
            }
        }
    }
}

// Fused classifier: logit = (relu(jk@W1+b1)*s+t)@w2 + b2, z never materialized.
__global__ __launch_bounds__(256) void k_cls(const u16* __restrict__ h0, const u16* __restrict__ h1,
                                             const u16* __restrict__ h2, const u16* __restrict__ h3,
                                             const u16* __restrict__ W1c, const float* __restrict__ wpad,
                                             const float* __restrict__ w2p, const float* __restrict__ b2p2,
                                             const int* __restrict__ flag, void* __restrict__ dout) {
    __shared__ __align__(16) u16 sB[16384];  // one phase slice of W1c (32KB)
    __shared__ float sb1[256];
    __shared__ float sw2[512];
    __shared__ float sb2[2];
    __shared__ float part[4][16][2];
    int tid = threadIdx.x;
    if (tid < 256) sb1[tid] = wpad[OCB1 + tid];
    for (int i = tid; i < 512; i += 256) sw2[i] = w2p[i];
    if (tid < 2) sb2[tid] = b2p2[tid];

    int wv = __builtin_amdgcn_readfirstlane(tid >> 6);
    int lane = tid & 63;
    int quad = lane >> 4, jc = lane & 15;
    int pair = wv >> 1;      // row group (0/1)
    int half = wv & 1;       // column half (0/1)
    int nb = blockIdx.x * 32 + pair * 16;

    f32x4 acc[8] = {{0.f, 0.f, 0.f, 0.f}, {0.f, 0.f, 0.f, 0.f}, {0.f, 0.f, 0.f, 0.f}, {0.f, 0.f, 0.f, 0.f},
                    {0.f, 0.f, 0.f, 0.f}, {0.f, 0.f, 0.f, 0.f}, {0.f, 0.f, 0.f, 0.f}, {0.f, 0.f, 0.f, 0.f}};
    const u16* hs[4] = {h0, h1, h2, h3};

    int row = nb + jc;
    if (row > NN - 1) row = NN - 1;

#pragma unroll 1
    for (int l = 0; l < 4; l++) {
        __syncthreads();
        const u32* src = (const u32*)W1c + l * 8192;
        for (int i = tid; i < 8192; i += 256) ((u32*)sB)[i] = src[i];
        __syncthreads();
        const uint4* rp = (const uint4*)(hs[l] + (size_t)row * 64);
        uint4 a0u = rp[quad], a1u = rp[4 + quad];
        bf16x8 af0 = __builtin_bit_cast(bf16x8, a0u);
        bf16x8 af1 = __builtin_bit_cast(bf16x8, a1u);
#pragma unroll
        for (int jt = 0; jt < 8; jt++) {
            int ct = half * 8 + jt;
            bf16x8 b0 = *reinterpret_cast<const bf16x8*>(&sB[((0 * 16 + ct) * 64 + lane) * 8]);
            bf16x8 b1f = *reinterpret_cast<const bf16x8*>(&sB[((1 * 16 + ct) * 64 + lane) * 8]);
            acc[jt] = __builtin_amdgcn_mfma_f32_16x16x32_bf16(af0, b0, acc[jt], 0, 0, 0);
            acc[jt] = __builtin_amdgcn_mfma_f32_16x16x32_bf16(af1, b1f, acc[jt], 0, 0, 0);
        }
    }

    // epilogue: relu(acc+b1) dot w2' -> per-row logit partials
    float p0[4] = {0, 0, 0, 0}, p1[4] = {0, 0, 0, 0};
#pragma unroll
    for (int jt = 0; jt < 8; jt++) {
        int j = (half * 8 + jt) * 16 + jc;
        float b1v = sb1[j], wa = sw2[2 * j], wb = sw2[2 * j + 1];
#pragma unroll
        for (int r = 0; r < 4; r++) {
            float h = fmaxf(acc[jt][r] + b1v, 0.f);
            p0[r] = fmaf(h, wa, p0[r]);
            p1[r] = fmaf(h, wb, p1[r]);
        }
    }
#pragma unroll
    for (int off = 1; off < 16; off <<= 1) {
#pragma unroll
        for (int r = 0; r < 4; r++) {
            p0[r] += __shfl_xor(p0[r], off);
            p1[r] += __shfl_xor(p1[r], off);
        }
    }
    if (jc == 0) {
#pragma unroll
        for (int r = 0; r < 4; r++) {
            part[wv][quad * 4 + r][0] = p0[r];
            part[wv][quad * 4 + r][1] = p1[r];
        }
    }
    __syncthreads();
    if (tid < 32) {
        int rl = tid & 15, p = tid >> 4;
        int n = blockIdx.x * 32 + tid;
        if (n < NN) {
            float l0 = part[2 * p][rl][0] + part[2 * p + 1][rl][0] + sb2[0];
            float l1 = part[2 * p][rl][1] + part[2 * p + 1][rl][1] + sb2[1];
            if (flag[0] != 0) {
                u32 pack = (u32)f2bf(l0) | ((u32)f2bf(l1) << 16);
                *(u32*)((u16*)dout + LG_OFF + (size_t)n * 2) = pack;
            } else {
                float2 o = {l0, l1};
                *(float2*)((float*)dout + LG_OFF + (size_t)n * 2) = o;
            }
        }
    }
}

extern "C" void kernel_launch(void* const* d_in, const int* in_sizes, int n_in,
                              void* d_out, int out_size, void* d_ws, size_t ws_size,
                              hipStream_t stream) {
    const void* features = d_in[0];
    const int* ei = (const int*)d_in[1];
    const void* zin = d_in[2];

    char* w = (char*)d_ws;
    auto alloc = [&](size_t bytes) -> void* {
        void* p = (void*)w;
        w += (bytes + 255) & ~(size_t)255;
        return p;
    };
    u16* X0 = (u16*)alloc((size_t)NN * 128 * 2);
    u16* Tx1 = (u16*)alloc((size_t)NN * 128 * 2);   // layer0: U; layers1-3: Tx1 (64-wide)
    u16* Tx2 = (u16*)alloc((size_t)NN * 128 * 2);   // layer0: V1|V2 compact; layers1-3: Tx2
    u16* h0 = (u16*)alloc((size_t)NN * 64 * 2);
    u16* h1 = (u16*)alloc((size_t)NN * 64 * 2);
    u16* h2 = (u16*)alloc((size_t)NN * 64 * 2);
    u16* h3 = (u16*)alloc((size_t)NN * 64 * 2);
    u16* Dbuf = (u16*)alloc((size_t)NN * 64 * 2);   // layer0: D = X@(W0-W2)
    float* ewf = (float*)alloc((size_t)EE * 4);
    uint2* csr_meta = (uint2*)alloc((size_t)EE * 8);
    u64* dc = (u64*)alloc((size_t)NN * 8);       // packed (cnt<<32 | deg fixed-point)
    int* cursor = (int*)alloc((size_t)NN * 4);
    float* dis = (float*)alloc((size_t)NN * 4);
    int* offs = (int*)alloc((size_t)(NN + 1) * 4);
    u16* W2s = (u16*)alloc((size_t)16384 * 2);
    float* b2p = (float*)alloc((size_t)128 * 4);
    u16* W1c = (u16*)alloc((size_t)65536 * 2);
    float* w2p = (float*)alloc((size_t)512 * 4);
    float* b2p2 = (float*)alloc((size_t)2 * 4);
    u16* Wg0 = (u16*)alloc((size_t)24576 * 2);
    u16* Wf1 = (u16*)alloc((size_t)12288 * 2);
    u16* Wf2 = (u16*)alloc((size_t)12288 * 2);
    u16* Wf3 = (u16*)alloc((size_t)12288 * 2);
    float* wpad = (float*)alloc((size_t)OTOT * 4);
    int* flag = (int*)alloc(256);

    u16* V1 = Tx2;                   // compact N x 64
    u16* V2 = Tx2 + (size_t)NN * 64; // compact N x 64

    // zero dc + cursor (contiguous allocations)
    hipMemsetAsync(dc, 0, (size_t)((char*)dis - (char*)dc), stream);

    PtrTab tab;
    for (int i = 0; i < 20; i++) tab.p[i] = d_in[3 + i];

    k_detect<<<1, 256, 0, stream>>>((const u16*)features, flag);
    k_wconv<<<20, 256, 0, stream>>>(tab, flag, wpad);
    k_fold<<<33, 128, 0, stream>>>(wpad, W2s, b2p);
    k_foldc<<<65, 256, 0, stream>>>(wpad, W1c, w2p, b2p2);
    k_foldw0<<<24, 256, 0, stream>>>(wpad, Wg0);
    k_foldw<<<36, 256, 0, stream>>>(wpad, Wf1, Wf2, Wf3);
    k_x0<<<3125, 256, 0, stream>>>(features, flag, X0);
    // grid 1024 with (256,3) bounds: 4 blocks/CU resident (VGPR 80, LDS 133KB),
    // NO spill (R8 lesson: launch_bounds(256,4) forced VGPR 64 -> 1.67GB scratch)
    k_pae<<<1024, 256, 0, stream>>>(zin, wpad, W2s, b2p, ei, flag, ewf, d_out, dc);
    k_scan<<<1, 1024, 0, stream>>>(dc, offs, dis);
    k_csr<<<EE / 256, 256, 0, stream>>>(ei, ewf, dis, offs, cursor, csr_meta);

    // layer 0 (commuted: project-then-propagate, compact V split)
    k_gemm0<<<1563, 256, 0, stream>>>(X0, Wg0, Tx1 /*U*/, Dbuf);
    k_prop0a<<<12500, 256, 0, stream>>>(Tx1, csr_meta, offs, V1, V2);
    k_prop0b<<<12500, 256, 0, stream>>>(V1, V2, csr_meta, offs, Dbuf, h0, flag, d_out);
    // layer 1 (F=64)
    k_prop64<<<12500, 256, 0, stream>>>(h0, csr_meta, offs, Tx1, nullptr, 1.f, 0.f);
    k_prop64<<<12500, 256, 0, stream>>>(Tx1, csr_meta, offs, Tx2, h0, 2.f, -1.f);
    k_gemm<64><<<1563, 256, 0, stream>>>(h0, Tx1, Tx2, Wf1, h1, d_out, 64, flag);
    // layer 2
    k_prop64<<<12500, 256, 0, stream>>>(h1, csr_meta, offs, Tx1, nullptr, 1.f, 0.f);
    k_prop64<<<12500, 256, 0, stream>>>(Tx1, csr_meta, offs, Tx2, h1, 2.f, -1.f);
    k_gemm<64><<<1563, 256, 0, stream>>>(h1, Tx1, Tx2, Wf2, h2, d_out, 128, flag);
    // layer 3
    k_prop64<<<12500, 256, 0, stream>>>(h2, csr_meta, offs, Tx1, nullptr, 1.f, 0.f);
    k_prop64<<<12500, 256, 0, stream>>>(Tx1, csr_meta, offs, Tx2, h2, 2.f, -1.f);
    k_gemm<64><<<1563, 256, 0, stream>>>(h2, Tx1, Tx2, Wf3, h3, d_out, 192, flag);

    // fused classifier (z never materialized)
    k_cls<<<1563, 256, 0, stream>>>(h0, h1, h2, h3, W1c, wpad, w2p, b2p2, flag, d_out);
    (void)in_sizes; (void)n_in; (void)out_size; (void)ws_size;
}

// Round 10
// 856.494 us; speedup vs baseline: 1.3255x; 1.0351x over previous
//
#include <hip/hip_runtime.h>

#define NN 50000
#define EE 1600000

using u16 = unsigned short;
using u32 = unsigned int;
using u64 = unsigned long long;

typedef float f32x4 __attribute__((ext_vector_type(4)));
typedef float f32x2 __attribute__((ext_vector_type(2)));
typedef __bf16 bf16x8 __attribute__((ext_vector_type(8)));
typedef unsigned short u16x8 __attribute__((ext_vector_type(8)));

struct alignas(8) U16x4 { u16 a, b, c, d; };
struct PtrTab { const void* p[20]; };

// canonical fp32 weight-pad offsets
#define OW1 0
#define OB1 768
#define OG 896
#define OBB 1024
#define ORM 1152
#define ORV 1280
#define OW2 1408
#define OB2 17792
#define OCH0 17920
#define OCH1 42496
#define OCH2 54784
#define OCH3 67072
#define OCW1 79360
#define OCB1 144896
#define OCG 145152
#define OCBB 145408
#define OCRM 145664
#define OCRV 145920
#define OCW2 146176
#define OCB2 146688
#define OTOT 146690

// element offsets within d_out (dtype-independent in elements)
#define LG_OFF ((size_t)NN * 256)
#define EW_OFF ((size_t)NN * 256 + (size_t)NN * 2)

__device__ __forceinline__ float bf2f(u16 u) { return __builtin_bit_cast(float, (u32)u << 16); }
__device__ __forceinline__ float bfl(u32 u) { return __builtin_bit_cast(float, u << 16); }
__device__ __forceinline__ float bfh(u32 u) { return __builtin_bit_cast(float, u & 0xffff0000u); }
__device__ __forceinline__ u16 f2bf(float f) {
    u32 u = __builtin_bit_cast(u32, f);
    return (u16)((u + 0x7fffu + ((u >> 16) & 1u)) >> 16);
}

// Input dtype detector: flag=1 -> bf16 inputs, 0 -> fp32 inputs.
__global__ __launch_bounds__(256) void k_detect(const u16* __restrict__ f, int* __restrict__ flag) {
    __shared__ int bad;
    if (threadIdx.x == 0) bad = 0;
    __syncthreads();
    u16 u = f[threadIdx.x];
    int e = (u >> 7) & 0xFF;
    if (e >= 0x90) atomicAdd(&bad, 1);
    __syncthreads();
    if (threadIdx.x == 0) flag[0] = (bad < 16) ? 1 : 0;
}

// Convert all 20 weight arrays into canonical fp32 pad.
__global__ __launch_bounds__(256) void k_wconv(PtrTab tab, const int* __restrict__ flag,
                                               float* __restrict__ wpad) {
    const int SZ[20] = {768, 128, 128, 128, 128, 128, 16384, 128, 24576, 12288, 12288, 12288,
                        65536, 256, 256, 256, 256, 256, 512, 2};
    const int OF[20] = {OW1, OB1, OG, OBB, ORM, ORV, OW2, OB2, OCH0, OCH1, OCH2, OCH3,
                        OCW1, OCB1, OCG, OCBB, OCRM, OCRV, OCW2, OCB2};
    int a = blockIdx.x;
    int n = SZ[a];
    float* dst = wpad + OF[a];
    if (flag[0] != 0) {
        const u16* s = (const u16*)tab.p[a];
        for (int i = threadIdx.x; i < n; i += 256) dst[i] = bf2f(s[i]);
    } else {
        const float* s = (const float*)tab.p[a];
        for (int i = threadIdx.x; i < n; i += 256) dst[i] = s[i];
    }
}

// Fold PAE BN into W2 (MFMA B-frag swizzled bf16) + b2'. k-row permutation
// matches stage-1 MFMA output order in k_pae (kappa(kc,q,j), R6).
__global__ __launch_bounds__(128) void k_fold(const float* __restrict__ wpad,
                                              u16* __restrict__ W2s, float* __restrict__ b2p) {
    const float* g = wpad + OG;
    const float* b = wpad + OBB;
    const float* rm = wpad + ORM;
    const float* rv = wpad + ORV;
    const float* w2 = wpad + OW2;
    const float* b2 = wpad + OB2;
    int blk = blockIdx.x, tid = threadIdx.x;
    if (blk < 32) {
        int kc = blk >> 3, jt = blk & 7;
        int lane = tid & 63, jh = tid >> 6;
        int q = lane >> 4;
        for (int jj = 0; jj < 4; jj++) {
            int j = jh * 4 + jj;
            int k = kc * 32 + ((j < 4) ? (q * 4 + j) : (16 + q * 4 + (j - 4)));
            int jcol = jt * 16 + (lane & 15);
            float s = g[k] * rsqrtf(rv[k] + 1e-5f);
            W2s[((kc * 8 + jt) * 64 + lane) * 8 + j] = f2bf(s * w2[k * 128 + jcol]);
        }
    } else {
        if (tid < 128) {
            int j = tid;
            float acc = b2[j];
            for (int k = 0; k < 128; k++) {
                float s = g[k] * rsqrtf(rv[k] + 1e-5f);
                float t = b[k] - rm[k] * s;
                acc += t * w2[k * 128 + j];
            }
            b2p[j] = acc;
        }
    }
}

// Fold classifier weights: W1c = cls_w1 as MFMA B-fragments (bf16, phase-sliced),
// w2p[j][c] = s_j * cls_w2[j][c], b2p2[c] = cls_b2[c] + sum_j t_j * cls_w2[j][c].
__global__ __launch_bounds__(256) void k_foldc(const float* __restrict__ wpad,
                                               u16* __restrict__ W1c, float* __restrict__ w2p,
                                               float* __restrict__ b2p2) {
    int tid = threadIdx.x;
    if (blockIdx.x < 64) {
        const float* w1 = wpad + OCW1;
        int base = blockIdx.x * 1024 + tid * 4;
#pragma unroll
        for (int u = 0; u < 4; u++) {
            int gi = base + u;
            int j = gi & 7;
            int lane = (gi >> 3) & 63;
            int ct = (gi >> 9) & 15;
            int kc2 = (gi >> 13) & 1;
            int l = gi >> 14;
            int k = l * 64 + kc2 * 32 + ((lane >> 4) & 3) * 8 + j;
            int col = ct * 16 + (lane & 15);
            W1c[gi] = f2bf(w1[k * 256 + col]);
        }
    } else {
        __shared__ float red[8];
        int j = tid;
        float s = wpad[OCG + j] * rsqrtf(wpad[OCRV + j] + 1e-5f);
        float t = wpad[OCBB + j] - wpad[OCRM + j] * s;
        float w0 = wpad[OCW2 + j * 2], w1v = wpad[OCW2 + j * 2 + 1];
        w2p[j * 2] = s * w0;
        w2p[j * 2 + 1] = s * w1v;
        float c0 = t * w0, c1 = t * w1v;
#pragma unroll
        for (int off = 1; off < 64; off <<= 1) {
            c0 += __shfl_xor(c0, off);
            c1 += __shfl_xor(c1, off);
        }
        int wv = tid >> 6, lane = tid & 63;
        if (lane == 0) { red[wv * 2] = c0; red[wv * 2 + 1] = c1; }
        __syncthreads();
        if (tid == 0) b2p2[0] = wpad[OCB2] + red[0] + red[2] + red[4] + red[6];
        if (tid == 1) b2p2[1] = wpad[OCB2 + 1] + red[1] + red[3] + red[5] + red[7];
    }
}

// Fold layers 1-3 ChebConv weights into MFMA B-fragment order (bf16).
__global__ __launch_bounds__(256) void k_foldw(const float* __restrict__ wpad,
                                               u16* __restrict__ Wf1,
                                               u16* __restrict__ Wf2, u16* __restrict__ Wf3) {
    int b = blockIdx.x, tid = threadIdx.x;
    const float* src;
    u16* dst;
    if (b < 12)      { src = wpad + OCH1; dst = Wf1; }
    else if (b < 24) { src = wpad + OCH2; dst = Wf2; b -= 12; }
    else             { src = wpad + OCH3; dst = Wf3; b -= 24; }
    int base = b * 1024 + tid * 4;
#pragma unroll
    for (int u = 0; u < 4; u++) {
        int gi = base + u;
        int jj = gi & 7;
        int lane = (gi >> 3) & 63;
        int ct = (gi >> 9) & 3;
        int kt = gi >> 11;
        int k = kt * 32 + ((lane >> 4) & 3) * 8 + jj;
        int col = ct * 16 + (lane & 15);
        dst[gi] = f2bf(src[k * 64 + col]);
    }
}

// Fold layer-0 weights (commuted form): Wg0 = B-fragments of [W1 | W2 | W0-W2].
__global__ __launch_bounds__(256) void k_foldw0(const float* __restrict__ wpad,
                                                u16* __restrict__ Wg0) {
    const float* src = wpad + OCH0;  // [3][128][64]
    int tid = threadIdx.x;
    int base = blockIdx.x * 1024 + tid * 4;
#pragma unroll
    for (int u = 0; u < 4; u++) {
        int gi = base + u;
        int jj = gi & 7;
        int lane = (gi >> 3) & 63;
        int rest = gi >> 9;      // kt*12 + ct
        int ct = rest % 12;
        int kt = rest / 12;
        int k = kt * 32 + ((lane >> 4) & 3) * 8 + jj;
        int cl = (lane & 15);
        float v;
        if (ct < 4) {
            v = src[(1 * 128 + k) * 64 + ct * 16 + cl];                    // W1
        } else if (ct < 8) {
            v = src[(2 * 128 + k) * 64 + (ct - 4) * 16 + cl];              // W2
        } else {
            int c = (ct - 8) * 16 + cl;
            v = src[(0 * 128 + k) * 64 + c] - src[(2 * 128 + k) * 64 + c]; // W0-W2
        }
        Wg0[gi] = f2bf(v);
    }
}

// features (either dtype) -> bf16 X0.
__global__ __launch_bounds__(256) void k_x0(const void* __restrict__ feat, const int* __restrict__ flag,
                                            u16* __restrict__ X0) {
    int i = blockIdx.x * 256 + threadIdx.x;
    if (flag[0] != 0) {
        ((uint4*)X0)[i] = ((const uint4*)feat)[i];
    } else {
        const float4* f = (const float4*)feat;
        float4 a = f[2 * i], b = f[2 * i + 1];
        u16x8 o;
        o[0] = f2bf(a.x); o[1] = f2bf(a.y); o[2] = f2bf(a.z); o[3] = f2bf(a.w);
        o[4] = f2bf(b.x); o[5] = f2bf(b.y); o[6] = f2bf(b.z); o[7] = f2bf(b.w);
        ((uint4*)X0)[i] = __builtin_bit_cast(uint4, o);
    }
}

// PAE, v10: both layers MFMA + packed-f32x2 epilogue.
// Grid FIXED at 768 = 3 blocks/CU: 4/CU fails BOTH ways (R3: atomic bounce;
// R9: 4th block never co-schedules, occupancy DROPPED 30->25.5%, dur 222->248).
__global__ __launch_bounds__(256, 3) void k_pae(const void* __restrict__ zin, const float* __restrict__ wpad,
                                                const u16* __restrict__ W2sg, const float* __restrict__ b2p,
                                                const int* __restrict__ ei, const int* __restrict__ flag,
                                                float* __restrict__ ewf, void* __restrict__ dout,
                                                u64* __restrict__ dc) {
    __shared__ __align__(16) u16 sW2[16384];
    __shared__ float sB2[128];
    int tid = threadIdx.x;
    for (int i = tid; i < 8192; i += 256) ((u32*)sW2)[i] = ((const u32*)W2sg)[i];
    if (tid < 128) sB2[tid] = b2p[tid];
    __syncthreads();

    bool isbf = flag[0] != 0;
    int wv = __builtin_amdgcn_readfirstlane(tid >> 6);
    int lane = tid & 63;
    int quad = lane >> 4, lrow = lane & 15, jc = lane & 15;
    u32 qm = (quad == 0) ? 0xffffffffu : 0u;  // B-frag mask: only quad 0 supplies z

    // loop-invariant stage-1 operands: W1 A-frags (8 tiles) + b1 C-inits
    uint4 w1f[8];
    f32x4 cb[8];
#pragma unroll
    for (int kt = 0; kt < 8; kt++) {
        u32 a = 0, b = 0, c = 0;
        if (quad == 0) {
            int col = kt * 16 + lrow;
            a = (u32)f2bf(wpad[OW1 + 0 * 128 + col]) | ((u32)f2bf(wpad[OW1 + 1 * 128 + col]) << 16);
            b = (u32)f2bf(wpad[OW1 + 2 * 128 + col]) | ((u32)f2bf(wpad[OW1 + 3 * 128 + col]) << 16);
            c = (u32)f2bf(wpad[OW1 + 4 * 128 + col]) | ((u32)f2bf(wpad[OW1 + 5 * 128 + col]) << 16);
        }
        w1f[kt] = (uint4){a, b, c, 0u};
#pragma unroll
        for (int r = 0; r < 4; r++) cb[kt][r] = wpad[OB1 + kt * 16 + quad * 4 + r];
    }

    int gw = blockIdx.x * 4 + wv;
    const int ngroups = EE / 16;
    const int gstep = gridDim.x * 4;

    uint2 pb0, pb1, pb2;       // bf16 Z prefetch (24B row)
    float4 pf0, pf1, pf2;      // fp32 Z prefetch (48B row)
    if (gw < ngroups) {
        if (isbf) {
            const uint2* zp = (const uint2*)((const u16*)zin + (size_t)(gw * 16 + lrow) * 12);
            pb0 = zp[0]; pb1 = zp[1]; pb2 = zp[2];
        } else {
            const float4* zp = (const float4*)((const float*)zin + (size_t)(gw * 16 + lrow) * 12);
            pf0 = zp[0]; pf1 = zp[1]; pf2 = zp[2];
        }
    }

#pragma unroll 1
    for (int gidx = gw; gidx < ngroups; gidx += gstep) {
        int e0 = gidx * 16;
        float z1[6], z2[6];
        if (isbf) {
            z1[0] = bfl(pb0.x); z1[1] = bfh(pb0.x); z1[2] = bfl(pb0.y); z1[3] = bfh(pb0.y);
            z1[4] = bfl(pb1.x); z1[5] = bfh(pb1.x);
            z2[0] = bfl(pb1.y); z2[1] = bfh(pb1.y); z2[2] = bfl(pb2.x); z2[3] = bfh(pb2.x);
            z2[4] = bfl(pb2.y); z2[5] = bfh(pb2.y);
        } else {
            z1[0] = pf0.x; z1[1] = pf0.y; z1[2] = pf0.z; z1[3] = pf0.w; z1[4] = pf1.x; z1[5] = pf1.y;
            z2[0] = pf1.z; z2[1] = pf1.w; z2[2] = pf2.x; z2[3] = pf2.y; z2[4] = pf2.z; z2[5] = pf2.w;
        }
        // issue next group's Z loads now -- they complete under this group's compute
        int gn = gidx + gstep;
        if (gn < ngroups) {
            if (isbf) {
                const uint2* zp = (const uint2*)((const u16*)zin + (size_t)(gn * 16 + lrow) * 12);
                pb0 = zp[0]; pb1 = zp[1]; pb2 = zp[2];
            } else {
                const float4* zp = (const float4*)((const float*)zin + (size_t)(gn * 16 + lrow) * 12);
                pf0 = zp[0]; pf1 = zp[1]; pf2 = zp[2];
            }
        }
        // hoist epilogue row indices
        int rows[4];
        if (jc == 0) {
#pragma unroll
            for (int r = 0; r < 4; r++) rows[r] = ei[e0 + quad * 4 + r];
        }

        // build z B-frags (quad 0 only; lossless round-trip for bf16 inputs)
        u32 za0, za1, za2, zb0, zb1, zb2;
        asm("v_cvt_pk_bf16_f32 %0, %1, %2" : "=v"(za0) : "v"(z1[0]), "v"(z1[1]));
        asm("v_cvt_pk_bf16_f32 %0, %1, %2" : "=v"(za1) : "v"(z1[2]), "v"(z1[3]));
        asm("v_cvt_pk_bf16_f32 %0, %1, %2" : "=v"(za2) : "v"(z1[4]), "v"(z1[5]));
        asm("v_cvt_pk_bf16_f32 %0, %1, %2" : "=v"(zb0) : "v"(z2[0]), "v"(z2[1]));
        asm("v_cvt_pk_bf16_f32 %0, %1, %2" : "=v"(zb1) : "v"(z2[2]), "v"(z2[3]));
        asm("v_cvt_pk_bf16_f32 %0, %1, %2" : "=v"(zb2) : "v"(z2[4]), "v"(z2[5]));
        uint4 zu1 = {za0 & qm, za1 & qm, za2 & qm, 0u};
        uint4 zu2 = {zb0 & qm, zb1 & qm, zb2 & qm, 0u};
        bf16x8 zf1 = __builtin_bit_cast(bf16x8, zu1);
        bf16x8 zf2 = __builtin_bit_cast(bf16x8, zu2);

        // stage 1 + pack, encoding 1
        bf16x8 a1f[4], a2f[4];
        {
            f32x4 c1[8];
#pragma unroll
            for (int kt = 0; kt < 8; kt++)
                c1[kt] = __builtin_amdgcn_mfma_f32_16x16x32_bf16(
                    __builtin_bit_cast(bf16x8, w1f[kt]), zf1, cb[kt], 0, 0, 0);
#pragma unroll
            for (int kc = 0; kc < 4; kc++) {
                float h0 = fmaxf(c1[2 * kc][0], 0.f), h1 = fmaxf(c1[2 * kc][1], 0.f);
                float h2 = fmaxf(c1[2 * kc][2], 0.f), h3 = fmaxf(c1[2 * kc][3], 0.f);
                float h4 = fmaxf(c1[2 * kc + 1][0], 0.f), h5 = fmaxf(c1[2 * kc + 1][1], 0.f);
                float h6 = fmaxf(c1[2 * kc + 1][2], 0.f), h7 = fmaxf(c1[2 * kc + 1][3], 0.f);
                u32 p0, p1, p2, p3;
                asm("v_cvt_pk_bf16_f32 %0, %1, %2" : "=v"(p0) : "v"(h0), "v"(h1));
                asm("v_cvt_pk_bf16_f32 %0, %1, %2" : "=v"(p1) : "v"(h2), "v"(h3));
                asm("v_cvt_pk_bf16_f32 %0, %1, %2" : "=v"(p2) : "v"(h4), "v"(h5));
                asm("v_cvt_pk_bf16_f32 %0, %1, %2" : "=v"(p3) : "v"(h6), "v"(h7));
                uint4 au = {p0, p1, p2, p3};
                a1f[kc] = __builtin_bit_cast(bf16x8, au);
            }
        }
        // stage 1 + pack, encoding 2
        {
            f32x4 c2[8];
#pragma unroll
            for (int kt = 0; kt < 8; kt++)
                c2[kt] = __builtin_amdgcn_mfma_f32_16x16x32_bf16(
                    __builtin_bit_cast(bf16x8, w1f[kt]), zf2, cb[kt], 0, 0, 0);
#pragma unroll
            for (int kc = 0; kc < 4; kc++) {
                float h0 = fmaxf(c2[2 * kc][0], 0.f), h1 = fmaxf(c2[2 * kc][1], 0.f);
                float h2 = fmaxf(c2[2 * kc][2], 0.f), h3 = fmaxf(c2[2 * kc][3], 0.f);
                float h4 = fmaxf(c2[2 * kc + 1][0], 0.f), h5 = fmaxf(c2[2 * kc + 1][1], 0.f);
                float h6 = fmaxf(c2[2 * kc + 1][2], 0.f), h7 = fmaxf(c2[2 * kc + 1][3], 0.f);
                u32 p0, p1, p2, p3;
                asm("v_cvt_pk_bf16_f32 %0, %1, %2" : "=v"(p0) : "v"(h0), "v"(h1));
                asm("v_cvt_pk_bf16_f32 %0, %1, %2" : "=v"(p1) : "v"(h2), "v"(h3));
                asm("v_cvt_pk_bf16_f32 %0, %1, %2" : "=v"(p2) : "v"(h4), "v"(h5));
                asm("v_cvt_pk_bf16_f32 %0, %1, %2" : "=v"(p3) : "v"(h6), "v"(h7));
                uint4 au = {p0, p1, p2, p3};
                a2f[kc] = __builtin_bit_cast(bf16x8, au);
            }
        }

        // packed cosine accumulators: 6 independent f32x2 chains
        f32x2 numA = {0.f, 0.f}, numB = {0.f, 0.f};
        f32x2 q1A = {0.f, 0.f}, q1B = {0.f, 0.f};
        f32x2 q2A = {0.f, 0.f}, q2B = {0.f, 0.f};
        // jt NOT unrolled: keeps ds_read hoisting bounded (spill guard).
#pragma unroll 1
        for (int jt = 0; jt < 8; jt++) {
            f32x4 acc1 = {0.f, 0.f, 0.f, 0.f}, acc2 = {0.f, 0.f, 0.f, 0.f};
#pragma unroll
            for (int kc = 0; kc < 4; kc++) {
                bf16x8 bb = *reinterpret_cast<const bf16x8*>(&sW2[((kc * 8 + jt) * 64 + lane) * 8]);
                acc1 = __builtin_amdgcn_mfma_f32_16x16x32_bf16(a1f[kc], bb, acc1, 0, 0, 0);
                acc2 = __builtin_amdgcn_mfma_f32_16x16x32_bf16(a2f[kc], bb, acc2, 0, 0, 0);
            }
            float bbias = sB2[jt * 16 + jc];
            f32x2 bb2 = {bbias, bbias};
            f32x2 a1lo = {acc1[0], acc1[1]}, a1hi = {acc1[2], acc1[3]};
            f32x2 a2lo = {acc2[0], acc2[1]}, a2hi = {acc2[2], acc2[3]};
            f32x2 h1A, h1B, h2A, h2B;
            asm("v_pk_add_f32 %0, %1, %2" : "=v"(h1A) : "v"(a1lo), "v"(bb2));
            asm("v_pk_add_f32 %0, %1, %2" : "=v"(h1B) : "v"(a1hi), "v"(bb2));
            asm("v_pk_add_f32 %0, %1, %2" : "=v"(h2A) : "v"(a2lo), "v"(bb2));
            asm("v_pk_add_f32 %0, %1, %2" : "=v"(h2B) : "v"(a2hi), "v"(bb2));
            asm("v_pk_fma_f32 %0, %1, %2, %0" : "+v"(numA) : "v"(h1A), "v"(h2A));
            asm("v_pk_fma_f32 %0, %1, %2, %0" : "+v"(numB) : "v"(h1B), "v"(h2B));
            asm("v_pk_fma_f32 %0, %1, %2, %0" : "+v"(q1A) : "v"(h1A), "v"(h1A));
            asm("v_pk_fma_f32 %0, %1, %2, %0" : "+v"(q1B) : "v"(h1B), "v"(h1B));
            asm("v_pk_fma_f32 %0, %1, %2, %0" : "+v"(q2A) : "v"(h2A), "v"(h2A));
            asm("v_pk_fma_f32 %0, %1, %2, %0" : "+v"(q2B) : "v"(h2B), "v"(h2B));
        }
        float num[4] = {numA[0], numA[1], numB[0], numB[1]};
        float q1[4] = {q1A[0], q1A[1], q1B[0], q1B[1]};
        float q2[4] = {q2A[0], q2A[1], q2B[0], q2B[1]};
#pragma unroll
        for (int off = 1; off < 16; off <<= 1) {
#pragma unroll
            for (int r = 0; r < 4; r++) {
                num[r] += __shfl_xor(num[r], off);
                q1[r] += __shfl_xor(q1[r], off);
                q2[r] += __shfl_xor(q2[r], off);
            }
        }
        if (jc == 0) {
#pragma unroll
            for (int r = 0; r < 4; r++) {
                int e = e0 + quad * 4 + r;
                float den = fmaxf(sqrtf(q1[r]) * sqrtf(q2[r]), 1e-8f);
                float wgt = (num[r] / den + 1.f) * 0.5f;
                if (!(wgt == wgt)) wgt = 0.5f;  // NaN guard: makes failures localizable
                ewf[e] = wgt;
                if (isbf) ((u16*)dout)[EW_OFF + e] = f2bf(wgt);
                else ((float*)dout)[EW_OFF + e] = wgt;
                // one u64 atomic: hi32 = count(+1), lo32 = wgt in 8.23 fixed point
                u32 fx = (u32)(wgt * 8388608.f + 0.5f);
                atomicAdd(dc + rows[r], (((u64)1) << 32) | (u64)fx);
            }
        }
    }
}

// Exclusive scan of cnt (hi32 of dc) -> offs; fused dis = rsqrt(deg).
__global__ __launch_bounds__(1024) void k_scan(const u64* __restrict__ dc,
                                               int* __restrict__ offs, float* __restrict__ dis) {
    __shared__ int wsum[16];
    __shared__ int carry;
    int tid = threadIdx.x;
    int wv = tid >> 6, lane = tid & 63;
    if (tid == 0) carry = 0;
    __syncthreads();
    for (int c = 0; c < 49; c++) {
        int i = c * 1024 + tid;
        u64 v64 = (i < NN) ? dc[i] : 0ull;
        int v = (int)(v64 >> 32);
        if (i < NN) {
            float d = (float)(u32)v64 * (1.f / 8388608.f);
            dis[i] = d > 0.f ? rsqrtf(d) : 0.f;
        }
        int x = v;
#pragma unroll
        for (int off = 1; off < 64; off <<= 1) {
            int t = __shfl_up(x, off);
            if (lane >= off) x += t;
        }
        if (lane == 63) wsum[wv] = x;
        __syncthreads();
        if (tid < 16) {
            int s = wsum[tid];
#pragma unroll
            for (int off = 1; off < 16; off <<= 1) {
                int t = __shfl_up(s, off, 16);
                if (tid >= off) s += t;
            }
            wsum[tid] = s;
        }
        __syncthreads();
        int base = carry + (wv > 0 ? wsum[wv - 1] : 0);
        if (i < NN) offs[i] = base + x - v;
        __syncthreads();
        if (tid == 0) carry += wsum[15];
        __syncthreads();
    }
    if (tid == 0) offs[NN] = carry;
}

// CSR scatter: fused (col, norm) uint2 metadata — one 8B load per edge in prop.
__global__ __launch_bounds__(256) void k_csr(const int* __restrict__ ei, const float* __restrict__ ewf,
                                             const float* __restrict__ dis, const int* __restrict__ offs,
                                             int* __restrict__ cursor, uint2* __restrict__ csr_meta) {
    int e = blockIdx.x * 256 + threadIdx.x;
    int r = ei[e], c = ei[EE + e];
    float wgt = ewf[e];
    int pos = offs[r] + atomicAdd(cursor + r, 1);
    float nrm = -dis[r] * wgt * dis[c];
    csr_meta[pos] = make_uint2((u32)c, __builtin_bit_cast(u32, nrm));
}

// ---- propagation kernels ----
// R7: masked full-width tails (clamp idx to e-1, weight 0). R9: 4-slot wide
// iterations -- 32 edges in flight for 64-wide props (16 for 128-wide), so a
// typical deg~32 node completes in ONE iteration (was 2), halving the exposed
// meta->row dependent-load chains.

// Layer-0 first prop: 128-wide gather of U, output SPLIT into compact V1/V2.
__global__ __launch_bounds__(256) void k_prop0a(const u16* __restrict__ U, const uint2* __restrict__ csr_meta,
                                                const int* __restrict__ offs,
                                                u16* __restrict__ V1, u16* __restrict__ V2) {
    int lane = threadIdx.x & 63;
    int wv = threadIdx.x >> 6;
    int node = blockIdx.x * 4 + wv;
    int s = offs[node], e = offs[node + 1];
    int sub = lane >> 4;
    int fl = lane & 15;
    const uint4* sv = (const uint4*)U;  // row = 16 uint4 (128 bf16)
    float a[8] = {0, 0, 0, 0, 0, 0, 0, 0};
    int p = s;
    if (p < e) {
        int i0 = p + sub, i1 = p + 4 + sub, i2 = p + 8 + sub, i3 = p + 12 + sub;
        uint2 m0 = csr_meta[min(i0, e - 1)];
        uint2 m1 = csr_meta[min(i1, e - 1)];
        uint2 m2 = csr_meta[min(i2, e - 1)];
        uint2 m3 = csr_meta[min(i3, e - 1)];
        float w0 = (i0 < e) ? __builtin_bit_cast(float, m0.y) : 0.f;
        float w1 = (i1 < e) ? __builtin_bit_cast(float, m1.y) : 0.f;
        float w2 = (i2 < e) ? __builtin_bit_cast(float, m2.y) : 0.f;
        float w3 = (i3 < e) ? __builtin_bit_cast(float, m3.y) : 0.f;
        while (true) {
            uint4 v0 = sv[(size_t)m0.x * 16 + fl];
            uint4 v1 = sv[(size_t)m1.x * 16 + fl];
            uint4 v2 = sv[(size_t)m2.x * 16 + fl];
            uint4 v3 = sv[(size_t)m3.x * 16 + fl];
            float w0c = w0, w1c = w1, w2c = w2, w3c = w3;
            p += 16;
            bool more = p < e;
            if (more) {
                i0 = p + sub; i1 = p + 4 + sub; i2 = p + 8 + sub; i3 = p + 12 + sub;
                m0 = csr_meta[min(i0, e - 1)];
                m1 = csr_meta[min(i1, e - 1)];
                m2 = csr_meta[min(i2, e - 1)];
                m3 = csr_meta[min(i3, e - 1)];
                w0 = (i0 < e) ? __builtin_bit_cast(float, m0.y) : 0.f;
                w1 = (i1 < e) ? __builtin_bit_cast(float, m1.y) : 0.f;
                w2 = (i2 < e) ? __builtin_bit_cast(float, m2.y) : 0.f;
                w3 = (i3 < e) ? __builtin_bit_cast(float, m3.y) : 0.f;
            }
            a[0] = fmaf(w0c, bfl(v0.x), a[0]); a[1] = fmaf(w0c, bfh(v0.x), a[1]);
            a[2] = fmaf(w0c, bfl(v0.y), a[2]); a[3] = fmaf(w0c, bfh(v0.y), a[3]);
            a[4] = fmaf(w0c, bfl(v0.z), a[4]); a[5] = fmaf(w0c, bfh(v0.z), a[5]);
            a[6] = fmaf(w0c, bfl(v0.w), a[6]); a[7] = fmaf(w0c, bfh(v0.w), a[7]);
            a[0] = fmaf(w1c, bfl(v1.x), a[0]); a[1] = fmaf(w1c, bfh(v1.x), a[1]);
            a[2] = fmaf(w1c, bfl(v1.y), a[2]); a[3] = fmaf(w1c, bfh(v1.y), a[3]);
            a[4] = fmaf(w1c, bfl(v1.z), a[4]); a[5] = fmaf(w1c, bfh(v1.z), a[5]);
            a[6] = fmaf(w1c, bfl(v1.w), a[6]); a[7] = fmaf(w1c, bfh(v1.w), a[7]);
            a[0] = fmaf(w2c, bfl(v2.x), a[0]); a[1] = fmaf(w2c, bfh(v2.x), a[1]);
            a[2] = fmaf(w2c, bfl(v2.y), a[2]); a[3] = fmaf(w2c, bfh(v2.y), a[3]);
            a[4] = fmaf(w2c, bfl(v2.z), a[4]); a[5] = fmaf(w2c, bfh(v2.z), a[5]);
            a[6] = fmaf(w2c, bfl(v2.w), a[6]); a[7] = fmaf(w2c, bfh(v2.w), a[7]);
            a[0] = fmaf(w3c, bfl(v3.x), a[0]); a[1] = fmaf(w3c, bfh(v3.x), a[1]);
            a[2] = fmaf(w3c, bfl(v3.y), a[2]); a[3] = fmaf(w3c, bfh(v3.y), a[3]);
            a[4] = fmaf(w3c, bfl(v3.z), a[4]); a[5] = fmaf(w3c, bfh(v3.z), a[5]);
            a[6] = fmaf(w3c, bfl(v3.w), a[6]); a[7] = fmaf(w3c, bfh(v3.w), a[7]);
            if (!more) break;
        }
    }
#pragma unroll
    for (int i = 0; i < 8; i++) {
        a[i] += __shfl_xor(a[i], 16);
        a[i] += __shfl_xor(a[i], 32);
    }
    if (sub == 0) {
        uint4 ov;
        ov.x = (u32)f2bf(a[0]) | ((u32)f2bf(a[1]) << 16);
        ov.y = (u32)f2bf(a[2]) | ((u32)f2bf(a[3]) << 16);
        ov.z = (u32)f2bf(a[4]) | ((u32)f2bf(a[5]) << 16);
        ov.w = (u32)f2bf(a[6]) | ((u32)f2bf(a[7]) << 16);
        if (fl < 8) ((uint4*)V1)[(size_t)node * 8 + fl] = ov;
        else ((uint4*)V2)[(size_t)node * 8 + (fl - 8)] = ov;
    }
}

// Layer-0 second prop: gathers COMPACT V2 (N x 64), fuses combine
// h0 = relu(D + V1 + 2*S); writes h0 (bf16) and jk slice 0.
__global__ __launch_bounds__(256) void k_prop0b(const u16* __restrict__ V1, const u16* __restrict__ V2,
                                                const uint2* __restrict__ csr_meta,
                                                const int* __restrict__ offs, const u16* __restrict__ D,
                                                u16* __restrict__ h0out, const int* __restrict__ flag,
                                                void* __restrict__ jkout) {
    int lane = threadIdx.x & 63;
    int wv = threadIdx.x >> 6;
    int node = blockIdx.x * 4 + wv;
    int s = offs[node], e = offs[node + 1];
    int sub = lane >> 3;
    int fl = lane & 7;
    const uint4* sv = (const uint4*)V2;  // row = 8 uint4 (64 bf16)
    float a[8] = {0, 0, 0, 0, 0, 0, 0, 0};
    int p = s;
    if (p < e) {
        int i0 = p + sub, i1 = p + 8 + sub, i2 = p + 16 + sub, i3 = p + 24 + sub;
        uint2 m0 = csr_meta[min(i0, e - 1)];
        uint2 m1 = csr_meta[min(i1, e - 1)];
        uint2 m2 = csr_meta[min(i2, e - 1)];
        uint2 m3 = csr_meta[min(i3, e - 1)];
        float w0 = (i0 < e) ? __builtin_bit_cast(float, m0.y) : 0.f;
        float w1 = (i1 < e) ? __builtin_bit_cast(float, m1.y) : 0.f;
        float w2 = (i2 < e) ? __builtin_bit_cast(float, m2.y) : 0.f;
        float w3 = (i3 < e) ? __builtin_bit_cast(float, m3.y) : 0.f;
        while (true) {
            uint4 v0 = sv[(size_t)m0.x * 8 + fl];
            uint4 v1 = sv[(size_t)m1.x * 8 + fl];
            uint4 v2 = sv[(size_t)m2.x * 8 + fl];
            uint4 v3 = sv[(size_t)m3.x * 8 + fl];
            float w0c = w0, w1c = w1, w2c = w2, w3c = w3;
            p += 32;
            bool more = p < e;
            if (more) {
                i0 = p + sub; i1 = p + 8 + sub; i2 = p + 16 + sub; i3 = p + 24 + sub;
                m0 = csr_meta[min(i0, e - 1)];
                m1 = csr_meta[min(i1, e - 1)];
                m2 = csr_meta[min(i2, e - 1)];
                m3 = csr_meta[min(i3, e - 1)];
                w0 = (i0 < e) ? __builtin_bit_cast(float, m0.y) : 0.f;
                w1 = (i1 < e) ? __builtin_bit_cast(float, m1.y) : 0.f;
                w2 = (i2 < e) ? __builtin_bit_cast(float, m2.y) : 0.f;
                w3 = (i3 < e) ? __builtin_bit_cast(float, m3.y) : 0.f;
            }
            a[0] = fmaf(w0c, bfl(v0.x), a[0]); a[1] = fmaf(w0c, bfh(v0.x), a[1]);
            a[2] = fmaf(w0c, bfl(v0.y), a[2]); a[3] = fmaf(w0c, bfh(v0.y), a[3]);
            a[4] = fmaf(w0c, bfl(v0.z), a[4]); a[5] = fmaf(w0c, bfh(v0.z), a[5]);
            a[6] = fmaf(w0c, bfl(v0.w), a[6]); a[7] = fmaf(w0c, bfh(v0.w), a[7]);
            a[0] = fmaf(w1c, bfl(v1.x), a[0]); a[1] = fmaf(w1c, bfh(v1.x), a[1]);
            a[2] = fmaf(w1c, bfl(v1.y), a[2]); a[3] = fmaf(w1c, bfh(v1.y), a[3]);
            a[4] = fmaf(w1c, bfl(v1.z), a[4]); a[5] = fmaf(w1c, bfh(v1.z), a[5]);
            a[6] = fmaf(w1c, bfl(v1.w), a[6]); a[7] = fmaf(w1c, bfh(v1.w), a[7]);
            a[0] = fmaf(w2c, bfl(v2.x), a[0]); a[1] = fmaf(w2c, bfh(v2.x), a[1]);
            a[2] = fmaf(w2c, bfl(v2.y), a[2]); a[3] = fmaf(w2c, bfh(v2.y), a[3]);
            a[4] = fmaf(w2c, bfl(v2.z), a[4]); a[5] = fmaf(w2c, bfh(v2.z), a[5]);
            a[6] = fmaf(w2c, bfl(v2.w), a[6]); a[7] = fmaf(w2c, bfh(v2.w), a[7]);
            a[0] = fmaf(w3c, bfl(v3.x), a[0]); a[1] = fmaf(w3c, bfh(v3.x), a[1]);
            a[2] = fmaf(w3c, bfl(v3.y), a[2]); a[3] = fmaf(w3c, bfh(v3.y), a[3]);
            a[4] = fmaf(w3c, bfl(v3.z), a[4]); a[5] = fmaf(w3c, bfh(v3.z), a[5]);
            a[6] = fmaf(w3c, bfl(v3.w), a[6]); a[7] = fmaf(w3c, bfh(v3.w), a[7]);
            if (!more) break;
        }
    }
#pragma unroll
    for (int i = 0; i < 8; i++) {
        a[i] += __shfl_xor(a[i], 8);
        a[i] += __shfl_xor(a[i], 16);
        a[i] += __shfl_xor(a[i], 32);
    }
    if (sub == 0) {
        uint4 v1 = ((const uint4*)V1)[(size_t)node * 8 + fl];
        uint4 dv = ((const uint4*)D)[(size_t)node * 8 + fl];
        float o[8];
        o[0] = fmaf(2.f, a[0], bfl(v1.x) + bfl(dv.x)); o[1] = fmaf(2.f, a[1], bfh(v1.x) + bfh(dv.x));
        o[2] = fmaf(2.f, a[2], bfl(v1.y) + bfl(dv.y)); o[3] = fmaf(2.f, a[3], bfh(v1.y) + bfh(dv.y));
        o[4] = fmaf(2.f, a[4], bfl(v1.z) + bfl(dv.z)); o[5] = fmaf(2.f, a[5], bfh(v1.z) + bfh(dv.z));
        o[6] = fmaf(2.f, a[6], bfl(v1.w) + bfl(dv.w)); o[7] = fmaf(2.f, a[7], bfh(v1.w) + bfh(dv.w));
#pragma unroll
        for (int i = 0; i < 8; i++) o[i] = fmaxf(o[i], 0.f);
        uint4 ov;
        ov.x = (u32)f2bf(o[0]) | ((u32)f2bf(o[1]) << 16);
        ov.y = (u32)f2bf(o[2]) | ((u32)f2bf(o[3]) << 16);
        ov.z = (u32)f2bf(o[4]) | ((u32)f2bf(o[5]) << 16);
        ov.w = (u32)f2bf(o[6]) | ((u32)f2bf(o[7]) << 16);
        ((uint4*)h0out)[(size_t)node * 8 + fl] = ov;
        if (flag[0] != 0) {
            ((uint4*)jkout)[(size_t)node * 32 + fl] = ov;  // jk row = 32 uint4, slice 0
        } else {
            float* jf = (float*)jkout + (size_t)node * 256 + fl * 8;
#pragma unroll
            for (int i = 0; i < 8; i++) jf[i] = o[i];
        }
    }
}

// Layers 1-3 propagation: 64-wide gather, masked 4-slot iterations.
__global__ __launch_bounds__(256) void k_prop64(const u16* __restrict__ src, const uint2* __restrict__ csr_meta,
                                                const int* __restrict__ offs,
                                                u16* __restrict__ out, const u16* __restrict__ base,
                                                float alpha, float beta) {
    int lane = threadIdx.x & 63;
    int wv = threadIdx.x >> 6;
    int node = blockIdx.x * 4 + wv;
    int s = offs[node], e = offs[node + 1];
    int sub = lane >> 3;
    int fl = lane & 7;
    const uint4* sv = (const uint4*)src;  // row = 8 uint4 (64 bf16)
    float a[8] = {0, 0, 0, 0, 0, 0, 0, 0};
    int p = s;
    if (p < e) {
        int i0 = p + sub, i1 = p + 8 + sub, i2 = p + 16 + sub, i3 = p + 24 + sub;
        uint2 m0 = csr_meta[min(i0, e - 1)];
        uint2 m1 = csr_meta[min(i1, e - 1)];
        uint2 m2 = csr_meta[min(i2, e - 1)];
        uint2 m3 = csr_meta[min(i3, e - 1)];
        float w0 = (i0 < e) ? __builtin_bit_cast(float, m0.y) : 0.f;
        float w1 = (i1 < e) ? __builtin_bit_cast(float, m1.y) : 0.f;
        float w2 = (i2 < e) ? __builtin_bit_cast(float, m2.y) : 0.f;
        float w3 = (i3 < e) ? __builtin_bit_cast(float, m3.y) : 0.f;
        while (true) {
            uint4 v0 = sv[(size_t)m0.x * 8 + fl];
            uint4 v1 = sv[(size_t)m1.x * 8 + fl];
            uint4 v2 = sv[(size_t)m2.x * 8 + fl];
            uint4 v3 = sv[(size_t)m3.x * 8 + fl];
            float w0c = w0, w1c = w1, w2c = w2, w3c = w3;
            p += 32;
            bool more = p < e;
            if (more) {
                i0 = p + sub; i1 = p + 8 + sub; i2 = p + 16 + sub; i3 = p + 24 + sub;
                m0 = csr_meta[min(i0, e - 1)];
                m1 = csr_meta[min(i1, e - 1)];
                m2 = csr_meta[min(i2, e - 1)];
                m3 = csr_meta[min(i3, e - 1)];
                w0 = (i0 < e) ? __builtin_bit_cast(float, m0.y) : 0.f;
                w1 = (i1 < e) ? __builtin_bit_cast(float, m1.y) : 0.f;
                w2 = (i2 < e) ? __builtin_bit_cast(float, m2.y) : 0.f;
                w3 = (i3 < e) ? __builtin_bit_cast(float, m3.y) : 0.f;
            }
            a[0] = fmaf(w0c, bfl(v0.x), a[0]); a[1] = fmaf(w0c, bfh(v0.x), a[1]);
            a[2] = fmaf(w0c, bfl(v0.y), a[2]); a[3] = fmaf(w0c, bfh(v0.y), a[3]);
            a[4] = fmaf(w0c, bfl(v0.z), a[4]); a[5] = fmaf(w0c, bfh(v0.z), a[5]);
            a[6] = fmaf(w0c, bfl(v0.w), a[6]); a[7] = fmaf(w0c, bfh(v0.w), a[7]);
            a[0] = fmaf(w1c, bfl(v1.x), a[0]); a[1] = fmaf(w1c, bfh(v1.x), a[1]);
            a[2] = fmaf(w1c, bfl(v1.y), a[2]); a[3] = fmaf(w1c, bfh(v1.y), a[3]);
            a[4] = fmaf(w1c, bfl(v1.z), a[4]); a[5] = fmaf(w1c, bfh(v1.z), a[5]);
            a[6] = fmaf(w1c, bfl(v1.w), a[6]); a[7] = fmaf(w1c, bfh(v1.w), a[7]);
            a[0] = fmaf(w2c, bfl(v2.x), a[0]); a[1] = fmaf(w2c, bfh(v2.x), a[1]);
            a[2] = fmaf(w2c, bfl(v2.y), a[2]); a[3] = fmaf(w2c, bfh(v2.y), a[3]);
            a[4] = fmaf(w2c, bfl(v2.z), a[4]); a[5] = fmaf(w2c, bfh(v2.z), a[5]);
            a[6] = fmaf(w2c, bfl(v2.w), a[6]); a[7] = fmaf(w2c, bfh(v2.w), a[7]);
            a[0] = fmaf(w3c, bfl(v3.x), a[0]); a[1] = fmaf(w3c, bfh(v3.x), a[1]);
            a[2] = fmaf(w3c, bfl(v3.y), a[2]); a[3] = fmaf(w3c, bfh(v3.y), a[3]);
            a[4] = fmaf(w3c, bfl(v3.z), a[4]); a[5] = fmaf(w3c, bfh(v3.z), a[5]);
            a[6] = fmaf(w3c, bfl(v3.w), a[6]); a[7] = fmaf(w3c, bfh(v3.w), a[7]);
            if (!more) break;
        }
    }
#pragma unroll
    for (int i = 0; i < 8; i++) {
        a[i] += __shfl_xor(a[i], 8);
        a[i] += __shfl_xor(a[i], 16);
        a[i] += __shfl_xor(a[i], 32);
    }
    if (sub == 0) {
        float o[8];
#pragma unroll
        for (int i = 0; i < 8; i++) o[i] = alpha * a[i];
        if (beta != 0.f) {
            uint4 bv = ((const uint4*)base)[(size_t)node * 8 + fl];
            o[0] = fmaf(beta, bfl(bv.x), o[0]); o[1] = fmaf(beta, bfh(bv.x), o[1]);
            o[2] = fmaf(beta, bfl(bv.y), o[2]); o[3] = fmaf(beta, bfh(bv.y), o[3]);
            o[4] = fmaf(beta, bfl(bv.z), o[4]); o[5] = fmaf(beta, bfh(bv.z), o[5]);
            o[6] = fmaf(beta, bfl(bv.w), o[6]); o[7] = fmaf(beta, bfh(bv.w), o[7]);
        }
        uint4 ov;
        ov.x = (u32)f2bf(o[0]) | ((u32)f2bf(o[1]) << 16);
        ov.y = (u32)f2bf(o[2]) | ((u32)f2bf(o[3]) << 16);
        ov.z = (u32)f2bf(o[4]) | ((u32)f2bf(o[5]) << 16);
        ov.w = (u32)f2bf(o[6]) | ((u32)f2bf(o[7]) << 16);
        ((uint4*)out)[(size_t)node * 8 + fl] = ov;
    }
}

// Layer-0 projection gemm (commuted form): G = X @ [W1 | W2 | W0-W2],
// cols 0..127 -> U (N x 128), cols 128..191 -> D (N x 64). No relu.
__global__ __launch_bounds__(256) void k_gemm0(const u16* __restrict__ X0, const u16* __restrict__ Wg0,
                                               u16* __restrict__ U, u16* __restrict__ D) {
    __shared__ __align__(16) u16 sB[4 * 12 * 64 * 8];  // 48KB
    int tid = threadIdx.x;
    for (int i = tid; i < 12288; i += 256) ((u32*)sB)[i] = ((const u32*)Wg0)[i];
    __syncthreads();

    int wv = __builtin_amdgcn_readfirstlane(tid >> 6);
    int lane = tid & 63;
    int quad = lane >> 4, jc = lane & 15;
    int pair = wv >> 1;   // row group
    int half = wv & 1;    // column half (96 cols each)
    int nb = blockIdx.x * 32 + pair * 16;
    int row = nb + jc;
    if (row > NN - 1) row = NN - 1;

    uint4 av[4];
#pragma unroll
    for (int kt = 0; kt < 4; kt++)
        av[kt] = *(const uint4*)(X0 + (size_t)row * 128 + kt * 32 + quad * 8);

    f32x4 acc[6] = {{0.f, 0.f, 0.f, 0.f}, {0.f, 0.f, 0.f, 0.f}, {0.f, 0.f, 0.f, 0.f},
                    {0.f, 0.f, 0.f, 0.f}, {0.f, 0.f, 0.f, 0.f}, {0.f, 0.f, 0.f, 0.f}};
#pragma unroll
    for (int kt = 0; kt < 4; kt++) {
        bf16x8 af = __builtin_bit_cast(bf16x8, av[kt]);
#pragma unroll
        for (int ct = 0; ct < 6; ct++) {
            int g = half * 6 + ct;
            bf16x8 b0 = *reinterpret_cast<const bf16x8*>(&sB[((kt * 12 + g) * 64 + lane) * 8]);
            acc[ct] = __builtin_amdgcn_mfma_f32_16x16x32_bf16(af, b0, acc[ct], 0, 0, 0);
        }
    }

#pragma unroll
    for (int ct = 0; ct < 6; ct++) {
        int g = half * 6 + ct;
        int j = g * 16 + jc;
#pragma unroll
        for (int r = 0; r < 4; r++) {
            int n = nb + quad * 4 + r;
            if (n < NN) {
                float v = acc[ct][r];
                if (j < 128) U[(size_t)n * 128 + j] = f2bf(v);
                else D[(size_t)n * 64 + (j - 128)] = f2bf(v);
            }
        }
    }
}

// ChebConv mix via MFMA -> bf16 h + jk slice (out dtype). Layers 1-3 (F=64).
template <int F>
__global__ __launch_bounds__(256) void k_gemm(const u16* __restrict__ X0, const u16* __restrict__ X1,
                                              const u16* __restrict__ X2, const u16* __restrict__ Wf,
                                              u16* __restrict__ Hout, void* __restrict__ jk, int jkoff,
                                              const int* __restrict__ flag) {
    constexpr int KT = (3 * F) / 32;  // 6 (F=64)
    __shared__ __align__(16) u16 sB[KT * 4 * 64 * 8];
    int tid = threadIdx.x;
    for (int i = tid; i < KT * 4 * 64 * 4; i += 256) ((u32*)sB)[i] = ((const u32*)Wf)[i];
    __syncthreads();

    bool isbf = flag[0] != 0;
    int wv = __builtin_amdgcn_readfirstlane(tid >> 6);
    int lane = tid & 63;
    int quad = lane >> 4, jc = lane & 15;
    int pair = wv >> 1;   // row group
    int half = wv & 1;    // column half (32 cols)
    int nb = blockIdx.x * 32 + pair * 16;
    int row = nb + jc;
    if (row > NN - 1) row = NN - 1;

    uint4 av[KT];
#pragma unroll
    for (int kt = 0; kt < KT; kt++) {
        int kg = kt * 32 + quad * 8;
        const u16* Xp;
        int kk;
        if (kg < F) { Xp = X0; kk = kg; }
        else if (kg < 2 * F) { Xp = X1; kk = kg - F; }
        else { Xp = X2; kk = kg - 2 * F; }
        av[kt] = *(const uint4*)(Xp + (size_t)row * F + kk);
    }

    f32x4 acc0 = {0.f, 0.f, 0.f, 0.f}, acc1 = {0.f, 0.f, 0.f, 0.f};
#pragma unroll
    for (int kt = 0; kt < KT; kt++) {
        bf16x8 af = __builtin_bit_cast(bf16x8, av[kt]);
        bf16x8 b0 = *reinterpret_cast<const bf16x8*>(&sB[((kt * 4 + half * 2 + 0) * 64 + lane) * 8]);
        bf16x8 b1 = *reinterpret_cast<const bf16x8*>(&sB[((kt * 4 + half * 2 + 1) * 64 + lane) * 8]);
        acc0 = __builtin_amdgcn_mfma_f32_16x16x32_bf16(af, b0, acc0, 0, 0, 0);
        acc1 = __builtin_amdgcn_mfma_f32_16x16x32_bf16(af, b1, acc1, 0, 0, 0);
    }

#pragma unroll
    for (int ct = 0; ct < 2; ct++) {
        f32x4 a = ct ? acc1 : acc0;
        int j = (half * 2 + ct) * 16 + jc;
#pragma unroll
        for (int r = 0; r < 4; r++) {
            int n = nb + quad * 4 + r;
            if (n < NN) {
                float v = fmaxf(a[r], 0.f);
                Hout[(size_t)n * 64 + j] = f2bf(v);
                if (isbf) ((u16*)jk)[(size_t)n * 256 + jkoff + j] = f2bf(v);
                else ((float*)jk)[(size_t)n * 256 + jkoff + j] = v;
            }
        }
    }
}

// Fused classifier: logit = (relu(jk@W1+b1)*s+t)@w2 + b2, z never materialized.
__global__ __launch_bounds__(256) void k_cls(const u16* __restrict__ h0, const u16* __restrict__ h1,
                                             const u16* __restrict__ h2, const u16* __restrict__ h3,
                                             const u16* __restrict__ W1c, const float* __restrict__ wpad,
                                             const float* __restrict__ w2p, const float* __restrict__ b2p2,
                                             const int* __restrict__ flag, void* __restrict__ dout) {
    __shared__ __align__(16) u16 sB[16384];  // one phase slice of W1c (32KB)
    __shared__ float sb1[256];
    __shared__ float sw2[512];
    __shared__ float sb2[2];
    __shared__ float part[4][16][2];
    int tid = threadIdx.x;
    if (tid < 256) sb1[tid] = wpad[OCB1 + tid];
    for (int i = tid; i < 512; i += 256) sw2[i] = w2p[i];
    if (tid < 2) sb2[tid] = b2p2[tid];

    int wv = __builtin_amdgcn_readfirstlane(tid >> 6);
    int lane = tid & 63;
    int quad = lane >> 4, jc = lane & 15;
    int pair = wv >> 1;      // row group (0/1)
    int half = wv & 1;       // column half (0/1)
    int nb = blockIdx.x * 32 + pair * 16;

    f32x4 acc[8] = {{0.f, 0.f, 0.f, 0.f}, {0.f, 0.f, 0.f, 0.f}, {0.f, 0.f, 0.f, 0.f}, {0.f, 0.f, 0.f, 0.f},
                    {0.f, 0.f, 0.f, 0.f}, {0.f, 0.f, 0.f, 0.f}, {0.f, 0.f, 0.f, 0.f}, {0.f, 0.f, 0.f, 0.f}};
    const u16* hs[4] = {h0, h1, h2, h3};

    int row = nb + jc;
    if (row > NN - 1) row = NN - 1;

#pragma unroll 1
    for (int l = 0; l < 4; l++) {
        __syncthreads();
        const u32* src = (const u32*)W1c + l * 8192;
        for (int i = tid; i < 8192; i += 256) ((u32*)sB)[i] = src[i];
        __syncthreads();
        const uint4* rp = (const uint4*)(hs[l] + (size_t)row * 64);
        uint4 a0u = rp[quad], a1u = rp[4 + quad];
        bf16x8 af0 = __builtin_bit_cast(bf16x8, a0u);
        bf16x8 af1 = __builtin_bit_cast(bf16x8, a1u);
#pragma unroll
        for (int jt = 0; jt < 8; jt++) {
            int ct = half * 8 + jt;
            bf16x8 b0 = *reinterpret_cast<const bf16x8*>(&sB[((0 * 16 + ct) * 64 + lane) * 8]);
            bf16x8 b1f = *reinterpret_cast<const bf16x8*>(&sB[((1 * 16 + ct) * 64 + lane) * 8]);
            acc[jt] = __builtin_amdgcn_mfma_f32_16x16x32_bf16(af0, b0, acc[jt], 0, 0, 0);
            acc[jt] = __builtin_amdgcn_mfma_f32_16x16x32_bf16(af1, b1f, acc[jt], 0, 0, 0);
        }
    }

    // epilogue: relu(acc+b1) dot w2' -> per-row logit partials
    float p0[4] = {0, 0, 0, 0}, p1[4] = {0, 0, 0, 0};
#pragma unroll
    for (int jt = 0; jt < 8; jt++) {
        int j = (half * 8 + jt) * 16 + jc;
        float b1v = sb1[j], wa = sw2[2 * j], wb = sw2[2 * j + 1];
#pragma unroll
        for (int r = 0; r < 4; r++) {
            float h = fmaxf(acc[jt][r] + b1v, 0.f);
            p0[r] = fmaf(h, wa, p0[r]);
            p1[r] = fmaf(h, wb, p1[r]);
        }
    }
#pragma unroll
    for (int off = 1; off < 16; off <<= 1) {
#pragma unroll
        for (int r = 0; r < 4; r++) {
            p0[r] += __shfl_xor(p0[r], off);
            p1[r] += __shfl_xor(p1[r], off);
        }
    }
    if (jc == 0) {
#pragma unroll
        for (int r = 0; r < 4; r++) {
            part[wv][quad * 4 + r][0] = p0[r];
            part[wv][quad * 4 + r][1] = p1[r];
        }
    }
    __syncthreads();
    if (tid < 32) {
        int rl = tid & 15, p = tid >> 4;
        int n = blockIdx.x * 32 + tid;
        if (n < NN) {
            float l0 = part[2 * p][rl][0] + part[2 * p + 1][rl][0] + sb2[0];
            float l1 = part[2 * p][rl][1] + part[2 * p + 1][rl][1] + sb2[1];
            if (flag[0] != 0) {
                u32 pack = (u32)f2bf(l0) | ((u32)f2bf(l1) << 16);
                *(u32*)((u16*)dout + LG_OFF + (size_t)n * 2) = pack;
            } else {
                float2 o = {l0, l1};
                *(float2*)((float*)dout + LG_OFF + (size_t)n * 2) = o;
            }
        }
    }
}

extern "C" void kernel_launch(void* const* d_in, const int* in_sizes, int n_in,
                              void* d_out, int out_size, void* d_ws, size_t ws_size,
                              hipStream_t stream) {
    const void* features = d_in[0];
    const int* ei = (const int*)d_in[1];
    const void* zin = d_in[2];

    char* w = (char*)d_ws;
    auto alloc = [&](size_t bytes) -> void* {
        void* p = (void*)w;
        w += (bytes + 255) & ~(size_t)255;
        return p;
    };
    u16* X0 = (u16*)alloc((size_t)NN * 128 * 2);
    u16* Tx1 = (u16*)alloc((size_t)NN * 128 * 2);   // layer0: U; layers1-3: Tx1 (64-wide)
    u16* Tx2 = (u16*)alloc((size_t)NN * 128 * 2);   // layer0: V1|V2 compact; layers1-3: Tx2
    u16* h0 = (u16*)alloc((size_t)NN * 64 * 2);
    u16* h1 = (u16*)alloc((size_t)NN * 64 * 2);
    u16* h2 = (u16*)alloc((size_t)NN * 64 * 2);
    u16* h3 = (u16*)alloc((size_t)NN * 64 * 2);
    u16* Dbuf = (u16*)alloc((size_t)NN * 64 * 2);   // layer0: D = X@(W0-W2)
    float* ewf = (float*)alloc((size_t)EE * 4);
    uint2* csr_meta = (uint2*)alloc((size_t)EE * 8);
    u64* dc = (u64*)alloc((size_t)NN * 8);       // packed (cnt<<32 | deg fixed-point)
    int* cursor = (int*)alloc((size_t)NN * 4);
    float* dis = (float*)alloc((size_t)NN * 4);
    int* offs = (int*)alloc((size_t)(NN + 1) * 4);
    u16* W2s = (u16*)alloc((size_t)16384 * 2);
    float* b2p = (float*)alloc((size_t)128 * 4);
    u16* W1c = (u16*)alloc((size_t)65536 * 2);
    float* w2p = (float*)alloc((size_t)512 * 4);
    float* b2p2 = (float*)alloc((size_t)2 * 4);
    u16* Wg0 = (u16*)alloc((size_t)24576 * 2);
    u16* Wf1 = (u16*)alloc((size_t)12288 * 2);
    u16* Wf2 = (u16*)alloc((size_t)12288 * 2);
    u16* Wf3 = (u16*)alloc((size_t)12288 * 2);
    float* wpad = (float*)alloc((size_t)OTOT * 4);
    int* flag = (int*)alloc(256);

    u16* V1 = Tx2;                   // compact N x 64
    u16* V2 = Tx2 + (size_t)NN * 64; // compact N x 64

    // zero dc + cursor (contiguous allocations)
    hipMemsetAsync(dc, 0, (size_t)((char*)dis - (char*)dc), stream);

    PtrTab tab;
    for (int i = 0; i < 20; i++) tab.p[i] = d_in[3 + i];

    k_detect<<<1, 256, 0, stream>>>((const u16*)features, flag);
    k_wconv<<<20, 256, 0, stream>>>(tab, flag, wpad);
    k_fold<<<33, 128, 0, stream>>>(wpad, W2s, b2p);
    k_foldc<<<65, 256, 0, stream>>>(wpad, W1c, w2p, b2p2);
    k_foldw0<<<24, 256, 0, stream>>>(wpad, Wg0);
    k_foldw<<<36, 256, 0, stream>>>(wpad, Wf1, Wf2, Wf3);
    k_x0<<<3125, 256, 0, stream>>>(features, flag, X0);
    // 768 blocks = 3 blocks/CU, measured optimum (R3/R9: 4/CU fails both ways)
    k_pae<<<768, 256, 0, stream>>>(zin, wpad, W2s, b2p, ei, flag, ewf, d_out, dc);
    k_scan<<<1, 1024, 0, stream>>>(dc, offs, dis);
    k_csr<<<EE / 256, 256, 0, stream>>>(ei, ewf, dis, offs, cursor, csr_meta);

    // layer 0 (commuted: project-then-propagate, compact V split)
    k_gemm0<<<1563, 256, 0, stream>>>(X0, Wg0, Tx1 /*U*/, Dbuf);
    k_prop0a<<<12500, 256, 0, stream>>>(Tx1, csr_meta, offs, V1, V2);
    k_prop0b<<<12500, 256, 0, stream>>>(V1, V2, csr_meta, offs, Dbuf, h0, flag, d_out);
    // layer 1 (F=64)
    k_prop64<<<12500, 256, 0, stream>>>(h0, csr_meta, offs, Tx1, nullptr, 1.f, 0.f);
    k_prop64<<<12500, 256, 0, stream>>>(Tx1, csr_meta, offs, Tx2, h0, 2.f, -1.f);
    k_gemm<64><<<1563, 256, 0, stream>>>(h0, Tx1, Tx2, Wf1, h1, d_out, 64, flag);
    // layer 2
    k_prop64<<<12500, 256, 0, stream>>>(h1, csr_meta, offs, Tx1, nullptr, 1.f, 0.f);
    k_prop64<<<12500, 256, 0, stream>>>(Tx1, csr_meta, offs, Tx2, h1, 2.f, -1.f);
    k_gemm<64><<<1563, 256, 0, stream>>>(h1, Tx1, Tx2, Wf2, h2, d_out, 128, flag);
    // layer 3
    k_prop64<<<12500, 256, 0, stream>>>(h2, csr_meta, offs, Tx1, nullptr, 1.f, 0.f);
    k_prop64<<<12500, 256, 0, stream>>>(Tx1, csr_meta, offs, Tx2, h2, 2.f, -1.f);
    k_gemm<64><<<1563, 256, 0, stream>>>(h2, Tx1, Tx2, Wf3, h3, d_out, 192, flag);

    // fused classifier (z never materialized)
    k_cls<<<1563, 256, 0, stream>>>(h0, h1, h2, h3, W1c, wpad, w2p, b2p2, flag, d_out);
    (void)in_sizes; (void)n_in; (void)out_size; (void)ws_size;
}